// Round 8
// baseline (553.745 us; speedup 1.0000x reference)
//
#include <hip/hip_runtime.h>
#include <math.h>

typedef _Float16 f16;
using f16x8 = __attribute__((ext_vector_type(8))) _Float16;
using f32x4 = __attribute__((ext_vector_type(4))) float;

#define BATCH 2
#define SEQ   2048
#define DMODEL 4096
#define NH    32
#define NKV   8
#define HD    128
#define MTOK  (BATCH*SEQ)

// ---------------- f32 -> f16 convert ----------------
__global__ __launch_bounds__(256) void cvt_f32_f16_k(const float* __restrict__ in,
                                                     f16* __restrict__ out, int n8) {
  int i = blockIdx.x * 256 + threadIdx.x;
  if (i >= n8) return;
  const float4* p = reinterpret_cast<const float4*>(in) + (size_t)i * 2;
  float4 a = p[0], b = p[1];
  f16x8 o = { (f16)a.x, (f16)a.y, (f16)a.z, (f16)a.w,
              (f16)b.x, (f16)b.y, (f16)b.z, (f16)b.w };
  reinterpret_cast<f16x8*>(out)[i] = o;
}

// ------------- w[K][N] f32 -> wT[N][K] f16 (scale folds softmax scale into wq) -------------
__global__ __launch_bounds__(256) void transpose_cvt_k(const float* __restrict__ w,
                                                       f16* __restrict__ wt, int Kd, int Nd,
                                                       float scale) {
  __shared__ float tile[32][33];
  const int t = threadIdx.x;
  const int n0 = blockIdx.x * 32, k0 = blockIdx.y * 32;
  const int r = t >> 3, c4 = (t & 7) << 2;
  const float4 v = *reinterpret_cast<const float4*>(w + (size_t)(k0 + r) * Nd + n0 + c4);
  tile[r][c4 + 0] = v.x; tile[r][c4 + 1] = v.y; tile[r][c4 + 2] = v.z; tile[r][c4 + 3] = v.w;
  __syncthreads();
  union { f16 h[4]; ushort4 u4; } pk;
  pk.h[0] = (f16)(tile[c4 + 0][r] * scale);
  pk.h[1] = (f16)(tile[c4 + 1][r] * scale);
  pk.h[2] = (f16)(tile[c4 + 2][r] * scale);
  pk.h[3] = (f16)(tile[c4 + 3][r] * scale);
  *reinterpret_cast<ushort4*>(wt + (size_t)(n0 + r) * Kd + k0 + c4) = pk.u4;
}

// ------------- merged wk|wv transpose: blockIdx.z picks source; dst offset by z*Nd*Kd -------------
__global__ __launch_bounds__(256) void transpose_cvt2_k(const float* __restrict__ w0,
                                                        const float* __restrict__ w1,
                                                        f16* __restrict__ wt, int Kd, int Nd) {
  __shared__ float tile[32][33];
  const float* w = blockIdx.z ? w1 : w0;
  f16* dst = wt + (size_t)blockIdx.z * Nd * Kd;
  const int t = threadIdx.x;
  const int n0 = blockIdx.x * 32, k0 = blockIdx.y * 32;
  const int r = t >> 3, c4 = (t & 7) << 2;
  const float4 v = *reinterpret_cast<const float4*>(w + (size_t)(k0 + r) * Nd + n0 + c4);
  tile[r][c4 + 0] = v.x; tile[r][c4 + 1] = v.y; tile[r][c4 + 2] = v.z; tile[r][c4 + 3] = v.w;
  __syncthreads();
  union { f16 h[4]; ushort4 u4; } pk;
  pk.h[0] = (f16)tile[c4 + 0][r];
  pk.h[1] = (f16)tile[c4 + 1][r];
  pk.h[2] = (f16)tile[c4 + 2][r];
  pk.h[3] = (f16)tile[c4 + 3][r];
  *reinterpret_cast<ushort4*>(dst + (size_t)(n0 + r) * Kd + k0 + c4) = pk.u4;
}

// ------------- 128^2 GEMM. MODE 3: merged K|V projection (N=2048) -------------
template<int MODE>
__global__ __launch_bounds__(256) void gemm_bt_k(const f16* __restrict__ A,
                                                 const f16* __restrict__ BT,
                                                 void* __restrict__ Cv,
                                                 int M, int N, int K) {
  __shared__ f16 Alds[128 * 64];
  __shared__ f16 Blds[128 * 64];
  const int t = threadIdx.x, lane = t & 63, w = t >> 6;
  const int nbn = N >> 7;
  const int nwg = gridDim.x;
  const int cpx = nwg >> 3;
  const int bid = blockIdx.x;
  const int swz = (bid & 7) * cpx + (bid >> 3);
  const int bm = swz / nbn, bn = swz % nbn;
  const size_t m0 = (size_t)bm << 7, n0 = (size_t)bn << 7;

  const int srow = t >> 3;
  const int sslot = t & 7;
  char* ldsAw = (char*)Alds + w * 1024;
  char* ldsBw = (char*)Blds + w * 1024;

  f32x4 acc[4][4];
#pragma unroll
  for (int i = 0; i < 4; i++)
#pragma unroll
    for (int j = 0; j < 4; j++) acc[i][j] = f32x4{0.f, 0.f, 0.f, 0.f};

  const int wr = (w >> 1) << 6, wc = (w & 1) << 6;
  const int ll = lane & 15, lg = lane >> 4;

  for (int kt = 0; kt < K; kt += 64) {
    __syncthreads();
#pragma unroll
    for (int p = 0; p < 4; p++) {
      const int row = srow + (p << 5);
      const int ssrc = (sslot ^ (row & 7)) << 3;
      const f16* gA = A + (m0 + row) * (size_t)K + kt + ssrc;
      __builtin_amdgcn_global_load_lds((const __attribute__((address_space(1))) void*)gA,
          (__attribute__((address_space(3))) void*)(ldsAw + p * 4096), 16, 0, 0);
      const f16* gB = BT + (n0 + row) * (size_t)K + kt + ssrc;
      __builtin_amdgcn_global_load_lds((const __attribute__((address_space(1))) void*)gB,
          (__attribute__((address_space(3))) void*)(ldsBw + p * 4096), 16, 0, 0);
    }
    __syncthreads();
#pragma unroll
    for (int kk = 0; kk < 2; kk++) {
      f16x8 af[4], bfr[4];
      const int slot = (kk << 2) + lg;
#pragma unroll
      for (int i = 0; i < 4; i++) {
        const int r = wr + (i << 4) + ll;
        af[i] = *reinterpret_cast<const f16x8*>((const char*)Alds + r * 128 + ((slot ^ (r & 7)) << 4));
      }
#pragma unroll
      for (int j = 0; j < 4; j++) {
        const int r = wc + (j << 4) + ll;
        bfr[j] = *reinterpret_cast<const f16x8*>((const char*)Blds + r * 128 + ((slot ^ (r & 7)) << 4));
      }
#pragma unroll
      for (int i = 0; i < 4; i++)
#pragma unroll
        for (int j = 0; j < 4; j++)
          acc[i][j] = __builtin_amdgcn_mfma_f32_16x16x32_f16(af[i], bfr[j], acc[i][j], 0, 0, 0);
    }
  }

#pragma unroll
  for (int i = 0; i < 4; i++) {
    const size_t mrow = m0 + wr + (i << 4) + (lg << 2);
#pragma unroll
    for (int j = 0; j < 4; j++) {
      const size_t ncol = n0 + wc + (j << 4) + ll;
      if (MODE == 0) {
        f16* C = (f16*)Cv;
#pragma unroll
        for (int r = 0; r < 4; r++) C[(mrow + r) * N + ncol] = (f16)acc[i][j][r];
      } else if (MODE == 2) {
        float* C = (float*)Cv;
#pragma unroll
        for (int r = 0; r < 4; r++) C[(mrow + r) * N + ncol] = acc[i][j][r];
      } else if (MODE == 3) {
        f16* Kc = (f16*)Cv;
        f16* Vt = (f16*)Cv + (size_t)MTOK * NKV * HD;
        if ((int)ncol < 1024) {
#pragma unroll
          for (int r = 0; r < 4; r++) Kc[(mrow + r) * 1024 + ncol] = (f16)acc[i][j][r];
        } else {
          const int nc = (int)ncol - 1024;
          const int kvh = nc >> 7, d = nc & 127;
          const int b = (int)(mrow >> 11), sc = (int)(mrow & 2047);
          union { f16 h[4]; ushort4 u4; } pk;
#pragma unroll
          for (int r = 0; r < 4; r++) pk.h[r] = (f16)acc[i][j][r];
          *reinterpret_cast<ushort4*>(Vt + (((size_t)(b * NKV + kvh) * HD + d) * SEQ + sc)) = pk.u4;
        }
      }
    }
  }
}

// ------------- 256^2 8-phase GEMM (T2+T3+T4+T5) for the two 4096^3 GEMMs -------------
template<int MODE>
__global__ __launch_bounds__(512, 2) void gemm256_k(const f16* __restrict__ A,
                                                    const f16* __restrict__ BT,
                                                    void* __restrict__ Cv,
                                                    int M, int N, int K) {
  __shared__ f16 lds[2 * 4 * 128 * 64];   // 128 KB
  char* ldsb = (char*)lds;

  const int t = threadIdx.x, lane = t & 63, w = t >> 6;
  const int wm = w >> 2, wn = w & 3;
  const int ll = lane & 15, lg = lane >> 4;
  const int nbn = N >> 8;
  const int nwg = gridDim.x, cpx = nwg >> 3, bid = blockIdx.x;
  const int swz = (bid & 7) * cpx + (bid >> 3);
  const int bm = swz / nbn, bn = swz % nbn;
  const size_t m0 = (size_t)bm << 8, n0 = (size_t)bn << 8;
  const int NT = K >> 6;

  auto stage = [&](int bufI, int unit, int ktS) {
    const f16* base = (unit < 2) ? (A + (m0 + (size_t)(unit & 1) * 128) * (size_t)K)
                                 : (BT + (n0 + (size_t)(unit & 1) * 128) * (size_t)K);
#pragma unroll
    for (int rr = 0; rr < 2; rr++) {
      const int u = t + rr * 512;
      const int row = u >> 3, lin = u & 7;
      const int slot = lin ^ (row & 7);
      const f16* src = base + (size_t)row * K + ktS + slot * 8;
      char* dst = ldsb + (size_t)(bufI * 4 + unit) * 16384 + (size_t)(w * 64 + rr * 512) * 16;
      __builtin_amdgcn_global_load_lds((const __attribute__((address_space(1))) void*)src,
          (__attribute__((address_space(3))) void*)dst, 16, 0, 0);
    }
  };

  f32x4 acc[8][4];
#pragma unroll
  for (int i = 0; i < 8; i++)
#pragma unroll
    for (int j = 0; j < 4; j++) acc[i][j] = f32x4{0.f, 0.f, 0.f, 0.f};

  f16x8 af[4][2];
  f16x8 bfr[2][2][2];

  stage(0, 0, 0); stage(0, 2, 0); stage(0, 3, 0); stage(0, 1, 0);
  stage(1, 0, 64); stage(1, 2, 64); stage(1, 3, 64);
  asm volatile("s_waitcnt vmcnt(6)" ::: "memory");
  __builtin_amdgcn_sched_barrier(0);
  __builtin_amdgcn_s_barrier();

#define PH(RBUF, RDA, RDB, SBUF, SUNIT, STILE, VM, MH, NHQ) do {                          \
    if ((RDA) >= 0) {                                                                     \
      const char* ab = ldsb + (size_t)((RBUF) * 4 + (RDA)) * 16384;                       \
      _Pragma("unroll") for (int mi = 0; mi < 4; mi++)                                    \
        _Pragma("unroll") for (int kk = 0; kk < 2; kk++)                                  \
          af[mi][kk] = *reinterpret_cast<const f16x8*>(ab + (mi * 32 + wm * 16 + ll) * 128\
                               + ((((kk << 2) + lg) ^ (ll & 7)) << 4));                   \
    }                                                                                     \
    if ((RDB) >= 0) {                                                                     \
      const char* bb = ldsb + (size_t)((RBUF) * 4 + 2 + (RDB)) * 16384;                   \
      _Pragma("unroll") for (int ni = 0; ni < 2; ni++)                                    \
        _Pragma("unroll") for (int kk = 0; kk < 2; kk++)                                  \
          bfr[RDB][ni][kk] = *reinterpret_cast<const f16x8*>(bb +                         \
                               (wn * 32 + ni * 16 + ll) * 128                             \
                               + ((((kk << 2) + lg) ^ (ll & 7)) << 4));                   \
    }                                                                                     \
    stage((SBUF), (SUNIT), ((STILE) & (NT - 1)) << 6);                                    \
    if (VM) { asm volatile("s_waitcnt vmcnt(6)" ::: "memory");                            \
              __builtin_amdgcn_sched_barrier(0); }                                        \
    __builtin_amdgcn_s_barrier();                                                         \
    asm volatile("s_waitcnt lgkmcnt(0)" ::: "memory");                                    \
    __builtin_amdgcn_sched_barrier(0);                                                    \
    __builtin_amdgcn_s_setprio(1);                                                        \
    _Pragma("unroll") for (int kk = 0; kk < 2; kk++)                                      \
      _Pragma("unroll") for (int mi = 0; mi < 4; mi++)                                    \
        _Pragma("unroll") for (int ni = 0; ni < 2; ni++)                                  \
          acc[(MH) * 4 + mi][(NHQ) * 2 + ni] = __builtin_amdgcn_mfma_f32_16x16x32_f16(    \
              af[mi][kk], bfr[NHQ][ni][kk], acc[(MH) * 4 + mi][(NHQ) * 2 + ni], 0, 0, 0); \
    __builtin_amdgcn_s_setprio(0);                                                        \
    __builtin_amdgcn_s_barrier();                                                         \
  } while (0)

  for (int tt = 0; tt < NT; tt += 2) {
    PH(0,  0,  0, 1, 1, tt + 1, false, 0, 0);
    PH(0, -1,  1, 0, 0, tt + 2, false, 0, 1);
    PH(0,  1, -1, 0, 2, tt + 2, false, 1, 0);
    PH(0, -1, -1, 0, 3, tt + 2, true , 1, 1);
    PH(1,  0,  0, 0, 1, tt + 2, false, 0, 0);
    PH(1, -1,  1, 1, 0, tt + 3, false, 0, 1);
    PH(1,  1, -1, 1, 2, tt + 3, false, 1, 0);
    PH(1, -1, -1, 1, 3, tt + 3, true , 1, 1);
  }
#undef PH

#pragma unroll
  for (int mh = 0; mh < 2; mh++)
#pragma unroll
    for (int mi = 0; mi < 4; mi++) {
      const size_t r0 = m0 + mh * 128 + mi * 32 + wm * 16 + lg * 4;
#pragma unroll
      for (int nh = 0; nh < 2; nh++)
#pragma unroll
        for (int ni = 0; ni < 2; ni++) {
          const size_t c = n0 + nh * 128 + wn * 32 + ni * 16 + ll;
          const f32x4 v = acc[mh * 4 + mi][nh * 2 + ni];
          if (MODE == 0) {
            f16* C = (f16*)Cv;
#pragma unroll
            for (int rr = 0; rr < 4; rr++) C[(r0 + rr) * N + c] = (f16)v[rr];
          } else {
            float* C = (float*)Cv;
#pragma unroll
            for (int rr = 0; rr < 4; rr++) C[(r0 + rr) * N + c] = v[rr];
          }
        }
    }
}

// ------------- flash attention v8: 32 q/wave (QBLK=64/block) -------------
// Same K/V staging per tile amortized over 2x MFMA (LDS pipe is the binding resource).
// Two 16-q halves processed sequentially (keeps VGPR peak ~124); PV shares V fragments.
__global__ __launch_bounds__(512, 2) void attn_k8(const f16* __restrict__ Q,
                                                  const f16* __restrict__ Kb,
                                                  const f16* __restrict__ VT,
                                                  f16* __restrict__ ctx) {
  __shared__ f16 Klds[2][64 * 128];   // 16 KB x2
  __shared__ f16 Vlds[2][128 * 64];   // 16 KB x2
  __shared__ f16 Plds[8][16 * 64];    // 2 KB/wave, reused by both halves (total 80 KB)

  const int t = threadIdx.x, lane = t & 63, w = t >> 6;
  const int bid = blockIdx.x;
  // grid = 512; 64 consecutive swz (= 2 (b,kvh) K/V sets = 2 MB) per XCD.
  const int swz = (bid & 7) * 64 + (bid >> 3);
  const int qt = swz & 31, kvh = (swz >> 5) & 7, b = swz >> 8;
  const int h = kvh * 4 + (w & 3);
  const int q0 = qt * 64 + (w >> 2) * 32;   // wave covers q0..q0+31 (two 16-row halves)
  const int ll = lane & 15, lg = lane >> 4;

  const f16* Qb = Q + ((size_t)(b * SEQ + q0) * NH + h) * HD;
  const f16* Kh = Kb + ((size_t)b * SEQ * NKV + kvh) * HD;
  const f16* Vh = VT + ((size_t)(b * NKV + kvh)) * HD * SEQ;

  // Q fragments for both halves (MFMA B operand; wq prescaled by softmax scale).
  f16x8 qf0[4], qf1[4];
#pragma unroll
  for (int kd = 0; kd < 4; kd++) {
    qf0[kd] = *reinterpret_cast<const f16x8*>(Qb + (size_t)ll * (NH * HD) + kd * 32 + lg * 8);
    qf1[kd] = *reinterpret_cast<const f16x8*>(Qb + (size_t)(16 + ll) * (NH * HD) + kd * 32 + lg * 8);
  }

  float m0_ = -INFINITY, l0_ = 0.f, m1_ = -INFINITY, l1_ = 0.f;
  f32x4 o0[8], o1[8];
#pragma unroll
  for (int df = 0; df < 8; df++) { o0[df] = f32x4{0.f, 0.f, 0.f, 0.f}; o1[df] = f32x4{0.f, 0.f, 0.f, 0.f}; }

  const float THR = 11.5416f;  // 8 nats in log2 units

  auto stage = [&](int bufi, int kt) {
#pragma unroll
    for (int rr = 0; rr < 2; rr++) {
      const int u = w * 128 + rr * 64 + lane;
      const int krow = u >> 4, klin = u & 15;
      const int kslot = klin ^ (krow & 7);
      const f16* ksrc = Kh + (size_t)(kt + krow) * (NKV * HD) + kslot * 8;
      __builtin_amdgcn_global_load_lds((const __attribute__((address_space(1))) void*)ksrc,
          (__attribute__((address_space(3))) void*)((char*)&Klds[bufi][0] + (size_t)u * 16), 16, 0, 0);
      const int vrow = u >> 3, vlin = u & 7;
      const int vslot = vlin ^ (vrow & 7);
      const f16* vsrc = Vh + (size_t)vrow * SEQ + kt + vslot * 8;
      __builtin_amdgcn_global_load_lds((const __attribute__((address_space(1))) void*)vsrc,
          (__attribute__((address_space(3))) void*)((char*)&Vlds[bufi][0] + (size_t)u * 16), 16, 0, 0);
    }
  };

  // one half: QK -> online softmax -> pack P to LDS -> read pf (A-frag).
  auto half = [&](const char* Kt, const f16x8* qf, float& m_, float& l_, f32x4* o, f16x8* pf) {
    f32x4 s[4];
#pragma unroll
    for (int nf = 0; nf < 4; nf++) {
      f32x4 a = f32x4{0.f, 0.f, 0.f, 0.f};
#pragma unroll
      for (int kd = 0; kd < 4; kd++) {
        const int row = nf * 16 + ll;
        f16x8 kf = *reinterpret_cast<const f16x8*>(
            Kt + row * 256 + ((((kd << 2) + lg) ^ (row & 7)) << 4));
        a = __builtin_amdgcn_mfma_f32_16x16x32_f16(kf, qf[kd], a, 0, 0, 0);
      }
      s[nf] = a;
    }

    float mx = s[0][0];
#pragma unroll
    for (int nf = 0; nf < 4; nf++)
#pragma unroll
      for (int r = 0; r < 4; r++) mx = fmaxf(mx, s[nf][r]);

    if (!__all((int)(mx <= m_ + THR))) {
      float mr = fmaxf(mx, __shfl_xor(mx, 16, 64));
      mr = fmaxf(mr, __shfl_xor(mr, 32, 64));
      const float mn = fmaxf(m_, mr);
      const float corrq = __builtin_amdgcn_exp2f(m_ - mn);
      m_ = mn;
      l_ *= corrq;
#pragma unroll
      for (int r = 0; r < 4; r++) {
        const float c = __shfl(corrq, (lane & 48) | (lg * 4 + r), 64);
#pragma unroll
        for (int df = 0; df < 8; df++) o[df][r] *= c;
      }
    }

    float rs = 0.f;
#pragma unroll
    for (int nf = 0; nf < 4; nf++)
#pragma unroll
      for (int r = 0; r < 4; r++) {
        const float p = __builtin_amdgcn_exp2f(s[nf][r] - m_);
        s[nf][r] = p;
        rs += p;
      }
    rs += __shfl_xor(rs, 16, 64);
    rs += __shfl_xor(rs, 32, 64);
    l_ += rs;

    char* Pw = (char*)&Plds[w][0];
#pragma unroll
    for (int nf = 0; nf < 4; nf++) {
      union { f16 h[4]; ushort4 u4; } pk;
#pragma unroll
      for (int r = 0; r < 4; r++) pk.h[r] = (f16)s[nf][r];
      *reinterpret_cast<ushort4*>(Pw + ll * 128 + ((nf * 32 + lg * 8) ^ ((ll & 7) << 4))) = pk.u4;
    }
#pragma unroll
    for (int kf = 0; kf < 2; kf++)
      pf[kf] = *reinterpret_cast<const f16x8*>(Pw + ll * 128 + (((kf << 6) + (lg << 4)) ^ ((ll & 7) << 4)));
  };

  stage(0, 0);
  __syncthreads();

  for (int kt = 0; kt < SEQ; kt += 64) {
    const int buf = (kt >> 6) & 1;
    if (kt + 64 < SEQ) stage(buf ^ 1, kt + 64);

    const char* Kt = (const char*)Klds[buf];
    const char* Vt = (const char*)Vlds[buf];

    f16x8 pf0[2], pf1[2];
    half(Kt, qf0, m0_, l0_, o0, pf0);   // half A: rows q0..q0+15
    half(Kt, qf1, m1_, l1_, o1, pf1);   // half B: rows q0+16..q0+31 (P LDS reused; same-wave DS order)

    // PV joint: V fragments shared by both halves
#pragma unroll
    for (int kf = 0; kf < 2; kf++)
#pragma unroll
      for (int df = 0; df < 8; df++) {
        const int row = df * 16 + ll;
        f16x8 vf = *reinterpret_cast<const f16x8*>(
            Vt + row * 128 + ((((kf << 2) + lg) ^ (row & 7)) << 4));
        o0[df] = __builtin_amdgcn_mfma_f32_16x16x32_f16(pf0[kf], vf, o0[df], 0, 0, 0);
        o1[df] = __builtin_amdgcn_mfma_f32_16x16x32_f16(pf1[kf], vf, o1[df], 0, 0, 0);
      }

    __syncthreads();
  }

  // epilogue: both halves
  float inv0[4], inv1[4];
#pragma unroll
  for (int r = 0; r < 4; r++) {
    inv0[r] = 1.0f / __shfl(l0_, (lane & 48) | (lg * 4 + r), 64);
    inv1[r] = 1.0f / __shfl(l1_, (lane & 48) | (lg * 4 + r), 64);
  }
  f16* cb0 = ctx + ((size_t)(b * SEQ + q0) * NH + h) * HD;
  f16* cb1 = ctx + ((size_t)(b * SEQ + q0 + 16) * NH + h) * HD;
#pragma unroll
  for (int df = 0; df < 8; df++)
#pragma unroll
    for (int r = 0; r < 4; r++) {
      cb0[(size_t)(lg * 4 + r) * (NH * HD) + df * 16 + ll] = (f16)(o0[df][r] * inv0[r]);
      cb1[(size_t)(lg * 4 + r) * (NH * HD) + df * 16 + ll] = (f16)(o1[df][r] * inv1[r]);
    }
}

extern "C" void kernel_launch(void* const* d_in, const int* in_sizes, int n_in,
                              void* d_out, int out_size, void* d_ws, size_t ws_size,
                              hipStream_t stream) {
  (void)in_sizes; (void)n_in; (void)out_size;
  const float* x  = (const float*)d_in[0];
  const float* wq = (const float*)d_in[1];
  const float* wk = (const float*)d_in[2];
  const float* wv = (const float*)d_in[3];
  const float* wo = (const float*)d_in[4];
  float* out = (float*)d_out;

  const size_t SZ_X  = (size_t)MTOK * DMODEL * sizeof(f16);
  const size_t SZ_KV = (size_t)MTOK * NKV * HD * sizeof(f16);
  if (ws_size < 3 * SZ_X + 2 * SZ_KV) return;

  char* ws = (char*)d_ws;
  f16* xh  = (f16*)ws;                      // x f16; reused as ctx
  f16* wT  = (f16*)(ws + SZ_X);             // transposed weight (wq -> wk|wv -> wo)
  f16* Qb  = (f16*)(ws + 2 * SZ_X);
  f16* Kb  = (f16*)(ws + 3 * SZ_X);         // [B,S,NKV,HD]
  f16* VTb = (f16*)(ws + 3 * SZ_X + SZ_KV); // [B,NKV,HD,S] (right after Kb: MODE 3 relies on this)

  const float KSC2 = 0.08838834764831845f * 1.4426950408889634f;  // 1/sqrt(128)*log2(e)

  cvt_f32_f16_k<<<dim3(MTOK * DMODEL / 8 / 256), 256, 0, stream>>>(x, xh, MTOK * DMODEL / 8);

  // Q projection (wq prescaled -> attn needs no Q prescale)
  transpose_cvt_k<<<dim3(DMODEL / 32, DMODEL / 32), 256, 0, stream>>>(wq, wT, DMODEL, DMODEL, KSC2);
  gemm256_k<0><<<dim3((MTOK / 256) * (DMODEL / 256)), 512, 0, stream>>>(xh, wT, Qb, MTOK, DMODEL, DMODEL);

  // merged K|V projection: wT rows 0-1023 = wk^T, rows 1024-2047 = wv^T (one transpose dispatch)
  transpose_cvt2_k<<<dim3(NKV * HD / 32, DMODEL / 32, 2), 256, 0, stream>>>(wk, wv, wT, DMODEL, NKV * HD);
  gemm_bt_k<3><<<dim3((MTOK / 128) * (2048 / 128)), 256, 0, stream>>>(xh, wT, Kb, MTOK, 2048, DMODEL);

  attn_k8<<<dim3(BATCH * NKV * (SEQ / 64)), 512, 0, stream>>>(Qb, Kb, VTb, xh);

  transpose_cvt_k<<<dim3(DMODEL / 32, DMODEL / 32), 256, 0, stream>>>(wo, wT, DMODEL, DMODEL, 1.0f);
  gemm256_k<2><<<dim3((MTOK / 256) * (DMODEL / 256)), 512, 0, stream>>>(xh, wT, out, MTOK, DMODEL, DMODEL);
}

// Round 9
// 535.426 us; speedup vs baseline: 1.0342x; 1.0342x over previous
//
#include <hip/hip_runtime.h>
#include <math.h>

typedef _Float16 f16;
using f16x8 = __attribute__((ext_vector_type(8))) _Float16;
using f32x4 = __attribute__((ext_vector_type(4))) float;

#define BATCH 2
#define SEQ   2048
#define DMODEL 4096
#define NH    32
#define NKV   8
#define HD    128
#define MTOK  (BATCH*SEQ)

// ---------------- f32 -> f16 convert ----------------
__global__ __launch_bounds__(256) void cvt_f32_f16_k(const float* __restrict__ in,
                                                     f16* __restrict__ out, int n8) {
  int i = blockIdx.x * 256 + threadIdx.x;
  if (i >= n8) return;
  const float4* p = reinterpret_cast<const float4*>(in) + (size_t)i * 2;
  float4 a = p[0], b = p[1];
  f16x8 o = { (f16)a.x, (f16)a.y, (f16)a.z, (f16)a.w,
              (f16)b.x, (f16)b.y, (f16)b.z, (f16)b.w };
  reinterpret_cast<f16x8*>(out)[i] = o;
}

// ------------- w[K][N] f32 -> wT[N][K] f16 (scale folds softmax scale into wq) -------------
__global__ __launch_bounds__(256) void transpose_cvt_k(const float* __restrict__ w,
                                                       f16* __restrict__ wt, int Kd, int Nd,
                                                       float scale) {
  __shared__ float tile[32][33];
  const int t = threadIdx.x;
  const int n0 = blockIdx.x * 32, k0 = blockIdx.y * 32;
  const int r = t >> 3, c4 = (t & 7) << 2;
  const float4 v = *reinterpret_cast<const float4*>(w + (size_t)(k0 + r) * Nd + n0 + c4);
  tile[r][c4 + 0] = v.x; tile[r][c4 + 1] = v.y; tile[r][c4 + 2] = v.z; tile[r][c4 + 3] = v.w;
  __syncthreads();
  union { f16 h[4]; ushort4 u4; } pk;
  pk.h[0] = (f16)(tile[c4 + 0][r] * scale);
  pk.h[1] = (f16)(tile[c4 + 1][r] * scale);
  pk.h[2] = (f16)(tile[c4 + 2][r] * scale);
  pk.h[3] = (f16)(tile[c4 + 3][r] * scale);
  *reinterpret_cast<ushort4*>(wt + (size_t)(n0 + r) * Kd + k0 + c4) = pk.u4;
}

// ------------- merged wk|wv transpose -------------
__global__ __launch_bounds__(256) void transpose_cvt2_k(const float* __restrict__ w0,
                                                        const float* __restrict__ w1,
                                                        f16* __restrict__ wt, int Kd, int Nd) {
  __shared__ float tile[32][33];
  const float* w = blockIdx.z ? w1 : w0;
  f16* dst = wt + (size_t)blockIdx.z * Nd * Kd;
  const int t = threadIdx.x;
  const int n0 = blockIdx.x * 32, k0 = blockIdx.y * 32;
  const int r = t >> 3, c4 = (t & 7) << 2;
  const float4 v = *reinterpret_cast<const float4*>(w + (size_t)(k0 + r) * Nd + n0 + c4);
  tile[r][c4 + 0] = v.x; tile[r][c4 + 1] = v.y; tile[r][c4 + 2] = v.z; tile[r][c4 + 3] = v.w;
  __syncthreads();
  union { f16 h[4]; ushort4 u4; } pk;
  pk.h[0] = (f16)tile[c4 + 0][r];
  pk.h[1] = (f16)tile[c4 + 1][r];
  pk.h[2] = (f16)tile[c4 + 2][r];
  pk.h[3] = (f16)tile[c4 + 3][r];
  *reinterpret_cast<ushort4*>(dst + (size_t)(n0 + r) * Kd + k0 + c4) = pk.u4;
}

// ------------- 8-phase KV projection GEMM: BM=128, BN=256 (grid 32x8=256 = 1/CU) -------------
// Same counted-vmcnt schedule as gemm256_k with A-halves of 64 rows (8 KB units).
// Units: 0=A rows 0-63, 1=A rows 64-127 (1 gload each), 2=B cols 0-127, 3=B cols 128-255 (2 gloads).
// vmcnt(5) = gloads of one in-flight half-set (A0+B0+B1 = 1+2+2).
// Epilogue (K|V merged, N=2048): col<1024 -> K[B,S,NKV,HD]; col>=1024 -> VT[B,NKV,HD,SEQ].
__global__ __launch_bounds__(512, 2) void gemm_kv8_k(const f16* __restrict__ A,
                                                     const f16* __restrict__ BT,
                                                     f16* __restrict__ Kc,
                                                     f16* __restrict__ Vt,
                                                     int M, int N, int K) {
  __shared__ f16 lds[2 * 24576];   // 96 KB: per buf {A0 8K, A1 8K, B0 16K, B1 16K}
  char* ldsb = (char*)lds;

  const int t = threadIdx.x, lane = t & 63, w = t >> 6;
  const int wm = w >> 2, wn = w & 3;           // 2 M-waves x 4 N-waves, per-wave 64x64
  const int ll = lane & 15, lg = lane >> 4;
  const int nbn = N >> 8;                       // 8
  const int nwg = gridDim.x, cpx = nwg >> 3, bid = blockIdx.x;
  const int swz = (bid & 7) * cpx + (bid >> 3);
  const int bm = swz / nbn, bn = swz % nbn;
  const size_t m0 = (size_t)bm << 7, n0 = (size_t)bn << 8;
  const int NT = K >> 6;                        // 64 (pow2: stage-index wrap via &)

  const int uoff[4] = {0, 8192, 16384, 32768};

  auto stage = [&](int bufI, int unit, int ktS) {
    char* dstb = ldsb + (size_t)bufI * 49152 + uoff[unit];
    if (unit < 2) {
      const f16* base = A + (m0 + (size_t)(unit & 1) * 64) * (size_t)K;
      const int row = t >> 3, lin = t & 7;
      const int slot = lin ^ (row & 7);
      const f16* src = base + (size_t)row * K + ktS + slot * 8;
      __builtin_amdgcn_global_load_lds((const __attribute__((address_space(1))) void*)src,
          (__attribute__((address_space(3))) void*)(dstb + (size_t)t * 16), 16, 0, 0);
    } else {
      const f16* base = BT + (n0 + (size_t)(unit & 1) * 128) * (size_t)K;
#pragma unroll
      for (int rr = 0; rr < 2; rr++) {
        const int u = t + rr * 512;
        const int row = u >> 3, lin = u & 7;
        const int slot = lin ^ (row & 7);
        const f16* src = base + (size_t)row * K + ktS + slot * 8;
        __builtin_amdgcn_global_load_lds((const __attribute__((address_space(1))) void*)src,
            (__attribute__((address_space(3))) void*)(dstb + (size_t)u * 16), 16, 0, 0);
      }
    }
  };

  f32x4 acc[4][4];   // [MH*2+mi2][NHQ*2+ni2]
#pragma unroll
  for (int i = 0; i < 4; i++)
#pragma unroll
    for (int j = 0; j < 4; j++) acc[i][j] = f32x4{0.f, 0.f, 0.f, 0.f};

  f16x8 af[2][2];        // current A quadrant frags [mi2][kk]
  f16x8 bfr[2][2][2];    // [NHQ][ni2][kk], persists across phases

  // prologue: buf0 {A0,A1,B0,B1}; buf1 {A0,B0,B1}; wait buf0 (6 gloads) landed.
  stage(0, 0, 0); stage(0, 1, 0); stage(0, 2, 0); stage(0, 3, 0);
  stage(1, 0, 64); stage(1, 2, 64); stage(1, 3, 64);
  asm volatile("s_waitcnt vmcnt(5)" ::: "memory");
  __builtin_amdgcn_sched_barrier(0);
  __builtin_amdgcn_s_barrier();

#define PHK(RBUF, RDA, RDB, SBUF, SUNIT, STILE, VM, MH, NHQ) do {                         \
    if ((RDA) >= 0) {                                                                     \
      const char* ab = ldsb + (size_t)(RBUF) * 49152 + uoff[MH];                          \
      _Pragma("unroll") for (int mi2 = 0; mi2 < 2; mi2++)                                 \
        _Pragma("unroll") for (int kk = 0; kk < 2; kk++) {                                \
          const int ri = wm * 32 + mi2 * 16 + ll;                                         \
          af[mi2][kk] = *reinterpret_cast<const f16x8*>(ab + ri * 128                     \
                               + ((((kk << 2) + lg) ^ (ri & 7)) << 4));                   \
        }                                                                                 \
    }                                                                                     \
    if ((RDB) >= 0) {                                                                     \
      const char* bb = ldsb + (size_t)(RBUF) * 49152 + uoff[2 + (RDB)];                   \
      _Pragma("unroll") for (int ni2 = 0; ni2 < 2; ni2++)                                 \
        _Pragma("unroll") for (int kk = 0; kk < 2; kk++) {                                \
          const int ri = wn * 32 + ni2 * 16 + ll;                                         \
          bfr[RDB][ni2][kk] = *reinterpret_cast<const f16x8*>(bb + ri * 128               \
                               + ((((kk << 2) + lg) ^ (ri & 7)) << 4));                   \
        }                                                                                 \
    }                                                                                     \
    stage((SBUF), (SUNIT), ((STILE) & (NT - 1)) << 6);                                    \
    if (VM) { asm volatile("s_waitcnt vmcnt(5)" ::: "memory");                            \
              __builtin_amdgcn_sched_barrier(0); }                                        \
    __builtin_amdgcn_s_barrier();                                                         \
    asm volatile("s_waitcnt lgkmcnt(0)" ::: "memory");                                    \
    __builtin_amdgcn_sched_barrier(0);                                                    \
    __builtin_amdgcn_s_setprio(1);                                                        \
    _Pragma("unroll") for (int kk = 0; kk < 2; kk++)                                      \
      _Pragma("unroll") for (int mi2 = 0; mi2 < 2; mi2++)                                 \
        _Pragma("unroll") for (int ni2 = 0; ni2 < 2; ni2++)                               \
          acc[(MH) * 2 + mi2][(NHQ) * 2 + ni2] = __builtin_amdgcn_mfma_f32_16x16x32_f16(  \
              af[mi2][kk], bfr[NHQ][ni2][kk], acc[(MH) * 2 + mi2][(NHQ) * 2 + ni2],       \
              0, 0, 0);                                                                   \
    __builtin_amdgcn_s_setprio(0);                                                        \
    __builtin_amdgcn_s_barrier();                                                         \
  } while (0)

  for (int tt = 0; tt < NT; tt += 2) {
    PHK(0,  0,  0, 1, 1, tt + 1, false, 0, 0);  // read buf0 A0+B0; stage buf1.A1 (tile tt+1)
    PHK(0, -1,  1, 0, 0, tt + 2, false, 0, 1);  // read buf0 B1;    stage buf0.A0 (tile tt+2)
    PHK(0,  1, -1, 0, 2, tt + 2, false, 1, 0);  // read buf0 A1;    stage buf0.B0
    PHK(0, -1, -1, 0, 3, tt + 2, true , 1, 1);  //                  stage buf0.B1; vmcnt(5)
    PHK(1,  0,  0, 0, 1, tt + 2, false, 0, 0);  // read buf1 A0+B0; stage buf0.A1
    PHK(1, -1,  1, 1, 0, tt + 3, false, 0, 1);  // read buf1 B1;    stage buf1.A0 (tile tt+3)
    PHK(1,  1, -1, 1, 2, tt + 3, false, 1, 0);  // read buf1 A1;    stage buf1.B0
    PHK(1, -1, -1, 1, 3, tt + 3, true , 1, 1);  //                  stage buf1.B1; vmcnt(5)
  }
#undef PHK

  // epilogue: row = m0 + mh*64 + wm*32 + mi2*16 + lg*4 + rr ; col = n0 + nh*128 + wn*32 + ni2*16 + ll
#pragma unroll
  for (int mh = 0; mh < 2; mh++)
#pragma unroll
    for (int mi2 = 0; mi2 < 2; mi2++) {
      const size_t r0 = m0 + mh * 64 + wm * 32 + mi2 * 16 + lg * 4;
#pragma unroll
      for (int nh = 0; nh < 2; nh++)
#pragma unroll
        for (int ni2 = 0; ni2 < 2; ni2++) {
          const size_t c = n0 + nh * 128 + wn * 32 + ni2 * 16 + ll;
          const f32x4 v = acc[mh * 2 + mi2][nh * 2 + ni2];
          if ((int)c < 1024) {
#pragma unroll
            for (int rr = 0; rr < 4; rr++) Kc[(r0 + rr) * 1024 + c] = (f16)v[rr];
          } else {
            const int nc = (int)c - 1024;
            const int kvh = nc >> 7, d = nc & 127;
            const int b = (int)(r0 >> 11), sc = (int)(r0 & 2047);
            union { f16 h[4]; ushort4 u4; } pk;
#pragma unroll
            for (int rr = 0; rr < 4; rr++) pk.h[rr] = (f16)v[rr];
            *reinterpret_cast<ushort4*>(Vt + (((size_t)(b * NKV + kvh) * HD + d) * SEQ + sc)) = pk.u4;
          }
        }
    }
}

// ------------- 256^2 8-phase GEMM (T2+T3+T4+T5) for the two 4096^3 GEMMs -------------
template<int MODE>
__global__ __launch_bounds__(512, 2) void gemm256_k(const f16* __restrict__ A,
                                                    const f16* __restrict__ BT,
                                                    void* __restrict__ Cv,
                                                    int M, int N, int K) {
  __shared__ f16 lds[2 * 4 * 128 * 64];   // 128 KB
  char* ldsb = (char*)lds;

  const int t = threadIdx.x, lane = t & 63, w = t >> 6;
  const int wm = w >> 2, wn = w & 3;
  const int ll = lane & 15, lg = lane >> 4;
  const int nbn = N >> 8;
  const int nwg = gridDim.x, cpx = nwg >> 3, bid = blockIdx.x;
  const int swz = (bid & 7) * cpx + (bid >> 3);
  const int bm = swz / nbn, bn = swz % nbn;
  const size_t m0 = (size_t)bm << 8, n0 = (size_t)bn << 8;
  const int NT = K >> 6;

  auto stage = [&](int bufI, int unit, int ktS) {
    const f16* base = (unit < 2) ? (A + (m0 + (size_t)(unit & 1) * 128) * (size_t)K)
                                 : (BT + (n0 + (size_t)(unit & 1) * 128) * (size_t)K);
#pragma unroll
    for (int rr = 0; rr < 2; rr++) {
      const int u = t + rr * 512;
      const int row = u >> 3, lin = u & 7;
      const int slot = lin ^ (row & 7);
      const f16* src = base + (size_t)row * K + ktS + slot * 8;
      char* dst = ldsb + (size_t)(bufI * 4 + unit) * 16384 + (size_t)(w * 64 + rr * 512) * 16;
      __builtin_amdgcn_global_load_lds((const __attribute__((address_space(1))) void*)src,
          (__attribute__((address_space(3))) void*)dst, 16, 0, 0);
    }
  };

  f32x4 acc[8][4];
#pragma unroll
  for (int i = 0; i < 8; i++)
#pragma unroll
    for (int j = 0; j < 4; j++) acc[i][j] = f32x4{0.f, 0.f, 0.f, 0.f};

  f16x8 af[4][2];
  f16x8 bfr[2][2][2];

  stage(0, 0, 0); stage(0, 2, 0); stage(0, 3, 0); stage(0, 1, 0);
  stage(1, 0, 64); stage(1, 2, 64); stage(1, 3, 64);
  asm volatile("s_waitcnt vmcnt(6)" ::: "memory");
  __builtin_amdgcn_sched_barrier(0);
  __builtin_amdgcn_s_barrier();

#define PH(RBUF, RDA, RDB, SBUF, SUNIT, STILE, VM, MH, NHQ) do {                          \
    if ((RDA) >= 0) {                                                                     \
      const char* ab = ldsb + (size_t)((RBUF) * 4 + (RDA)) * 16384;                       \
      _Pragma("unroll") for (int mi = 0; mi < 4; mi++)                                    \
        _Pragma("unroll") for (int kk = 0; kk < 2; kk++)                                  \
          af[mi][kk] = *reinterpret_cast<const f16x8*>(ab + (mi * 32 + wm * 16 + ll) * 128\
                               + ((((kk << 2) + lg) ^ (ll & 7)) << 4));                   \
    }                                                                                     \
    if ((RDB) >= 0) {                                                                     \
      const char* bb = ldsb + (size_t)((RBUF) * 4 + 2 + (RDB)) * 16384;                   \
      _Pragma("unroll") for (int ni = 0; ni < 2; ni++)                                    \
        _Pragma("unroll") for (int kk = 0; kk < 2; kk++)                                  \
          bfr[RDB][ni][kk] = *reinterpret_cast<const f16x8*>(bb +                         \
                               (wn * 32 + ni * 16 + ll) * 128                             \
                               + ((((kk << 2) + lg) ^ (ll & 7)) << 4));                   \
    }                                                                                     \
    stage((SBUF), (SUNIT), ((STILE) & (NT - 1)) << 6);                                    \
    if (VM) { asm volatile("s_waitcnt vmcnt(6)" ::: "memory");                            \
              __builtin_amdgcn_sched_barrier(0); }                                        \
    __builtin_amdgcn_s_barrier();                                                         \
    asm volatile("s_waitcnt lgkmcnt(0)" ::: "memory");                                    \
    __builtin_amdgcn_sched_barrier(0);                                                    \
    __builtin_amdgcn_s_setprio(1);                                                        \
    _Pragma("unroll") for (int kk = 0; kk < 2; kk++)                                      \
      _Pragma("unroll") for (int mi = 0; mi < 4; mi++)                                    \
        _Pragma("unroll") for (int ni = 0; ni < 2; ni++)                                  \
          acc[(MH) * 4 + mi][(NHQ) * 2 + ni] = __builtin_amdgcn_mfma_f32_16x16x32_f16(    \
              af[mi][kk], bfr[NHQ][ni][kk], acc[(MH) * 4 + mi][(NHQ) * 2 + ni], 0, 0, 0); \
    __builtin_amdgcn_s_setprio(0);                                                        \
    __builtin_amdgcn_s_barrier();                                                         \
  } while (0)

  for (int tt = 0; tt < NT; tt += 2) {
    PH(0,  0,  0, 1, 1, tt + 1, false, 0, 0);
    PH(0, -1,  1, 0, 0, tt + 2, false, 0, 1);
    PH(0,  1, -1, 0, 2, tt + 2, false, 1, 0);
    PH(0, -1, -1, 0, 3, tt + 2, true , 1, 1);
    PH(1,  0,  0, 0, 1, tt + 2, false, 0, 0);
    PH(1, -1,  1, 1, 0, tt + 3, false, 0, 1);
    PH(1,  1, -1, 1, 2, tt + 3, false, 1, 0);
    PH(1, -1, -1, 1, 3, tt + 3, true , 1, 1);
  }
#undef PH

#pragma unroll
  for (int mh = 0; mh < 2; mh++)
#pragma unroll
    for (int mi = 0; mi < 4; mi++) {
      const size_t r0 = m0 + mh * 128 + mi * 32 + wm * 16 + lg * 4;
#pragma unroll
      for (int nh = 0; nh < 2; nh++)
#pragma unroll
        for (int ni = 0; ni < 2; ni++) {
          const size_t c = n0 + nh * 128 + wn * 32 + ni * 16 + ll;
          const f32x4 v = acc[mh * 4 + mi][nh * 2 + ni];
          if (MODE == 0) {
            f16* C = (f16*)Cv;
#pragma unroll
            for (int rr = 0; rr < 4; rr++) C[(r0 + rr) * N + c] = (f16)v[rr];
          } else {
            float* C = (float*)Cv;
#pragma unroll
            for (int rr = 0; rr < 4; rr++) C[(r0 + rr) * N + c] = v[rr];
          }
        }
    }
}

// ------------- flash attention (v7 verbatim: proven 185 us) -------------
__global__ __launch_bounds__(512) void attn_k9(const f16* __restrict__ Q,
                                               const f16* __restrict__ Kb,
                                               const f16* __restrict__ VT,
                                               f16* __restrict__ ctx) {
  __shared__ f16 Klds[2][64 * 128];   // 16 KB x2
  __shared__ f16 Vlds[2][128 * 64];   // 16 KB x2
  __shared__ f16 Plds[8][16 * 64];    // 2 KB/wave (total 80 KB)

  const int t = threadIdx.x, lane = t & 63, w = t >> 6;
  const int bid = blockIdx.x;
  const int swz = (bid & 7) * 128 + (bid >> 3);
  const int qt = swz & 63, kvh = (swz >> 6) & 7, b = swz >> 9;
  const int h = kvh * 4 + (w & 3);
  const int q0 = qt * 32 + (w >> 2) * 16;
  const int ll = lane & 15, lg = lane >> 4;

  const f16* Qb = Q + ((size_t)(b * SEQ + q0) * NH + h) * HD;
  const f16* Kh = Kb + ((size_t)b * SEQ * NKV + kvh) * HD;
  const f16* Vh = VT + ((size_t)(b * NKV + kvh)) * HD * SEQ;

  f16x8 qf[4];
#pragma unroll
  for (int kd = 0; kd < 4; kd++)
    qf[kd] = *reinterpret_cast<const f16x8*>(Qb + (size_t)ll * (NH * HD) + kd * 32 + lg * 8);

  float m_ = -INFINITY;
  float l_ = 0.f;
  f32x4 o[8];
#pragma unroll
  for (int df = 0; df < 8; df++) o[df] = f32x4{0.f, 0.f, 0.f, 0.f};

  const float THR = 11.5416f;  // 8 nats in log2 units

  auto stage = [&](int bufi, int kt) {
#pragma unroll
    for (int rr = 0; rr < 2; rr++) {
      const int u = w * 128 + rr * 64 + lane;
      const int krow = u >> 4, klin = u & 15;
      const int kslot = klin ^ (krow & 7);
      const f16* ksrc = Kh + (size_t)(kt + krow) * (NKV * HD) + kslot * 8;
      __builtin_amdgcn_global_load_lds((const __attribute__((address_space(1))) void*)ksrc,
          (__attribute__((address_space(3))) void*)((char*)&Klds[bufi][0] + (size_t)u * 16), 16, 0, 0);
      const int vrow = u >> 3, vlin = u & 7;
      const int vslot = vlin ^ (vrow & 7);
      const f16* vsrc = Vh + (size_t)vrow * SEQ + kt + vslot * 8;
      __builtin_amdgcn_global_load_lds((const __attribute__((address_space(1))) void*)vsrc,
          (__attribute__((address_space(3))) void*)((char*)&Vlds[bufi][0] + (size_t)u * 16), 16, 0, 0);
    }
  };

  stage(0, 0);
  __syncthreads();

  for (int kt = 0; kt < SEQ; kt += 64) {
    const int buf = (kt >> 6) & 1;
    if (kt + 64 < SEQ) stage(buf ^ 1, kt + 64);

    const char* Kt = (const char*)Klds[buf];
    const char* Vt = (const char*)Vlds[buf];

    f32x4 s[4];
#pragma unroll
    for (int nf = 0; nf < 4; nf++) {
      f32x4 a = f32x4{0.f, 0.f, 0.f, 0.f};
#pragma unroll
      for (int kd = 0; kd < 4; kd++) {
        const int row = nf * 16 + ll;
        f16x8 kf = *reinterpret_cast<const f16x8*>(
            Kt + row * 256 + ((((kd << 2) + lg) ^ (row & 7)) << 4));
        a = __builtin_amdgcn_mfma_f32_16x16x32_f16(kf, qf[kd], a, 0, 0, 0);
      }
      s[nf] = a;
    }

    float mx = s[0][0];
#pragma unroll
    for (int nf = 0; nf < 4; nf++)
#pragma unroll
      for (int r = 0; r < 4; r++) mx = fmaxf(mx, s[nf][r]);

    if (!__all((int)(mx <= m_ + THR))) {
      float mr = fmaxf(mx, __shfl_xor(mx, 16, 64));
      mr = fmaxf(mr, __shfl_xor(mr, 32, 64));
      const float mn = fmaxf(m_, mr);
      const float corrq = __builtin_amdgcn_exp2f(m_ - mn);
      m_ = mn;
      l_ *= corrq;
#pragma unroll
      for (int r = 0; r < 4; r++) {
        const float c = __shfl(corrq, (lane & 48) | (lg * 4 + r), 64);
#pragma unroll
        for (int df = 0; df < 8; df++) o[df][r] *= c;
      }
    }

    float rs = 0.f;
#pragma unroll
    for (int nf = 0; nf < 4; nf++)
#pragma unroll
      for (int r = 0; r < 4; r++) {
        const float p = __builtin_amdgcn_exp2f(s[nf][r] - m_);
        s[nf][r] = p;
        rs += p;
      }
    rs += __shfl_xor(rs, 16, 64);
    rs += __shfl_xor(rs, 32, 64);
    l_ += rs;

    char* Pw = (char*)&Plds[w][0];
#pragma unroll
    for (int nf = 0; nf < 4; nf++) {
      union { f16 h[4]; ushort4 u4; } pk;
#pragma unroll
      for (int r = 0; r < 4; r++) pk.h[r] = (f16)s[nf][r];
      *reinterpret_cast<ushort4*>(Pw + ll * 128 + ((nf * 32 + lg * 8) ^ ((ll & 7) << 4))) = pk.u4;
    }

    f16x8 pf[2];
#pragma unroll
    for (int kf = 0; kf < 2; kf++)
      pf[kf] = *reinterpret_cast<const f16x8*>(Pw + ll * 128 + (((kf << 6) + (lg << 4)) ^ ((ll & 7) << 4)));

#pragma unroll
    for (int kf = 0; kf < 2; kf++)
#pragma unroll
      for (int df = 0; df < 8; df++) {
        const int row = df * 16 + ll;
        f16x8 vf = *reinterpret_cast<const f16x8*>(
            Vt + row * 128 + ((((kf << 2) + lg) ^ (row & 7)) << 4));
        o[df] = __builtin_amdgcn_mfma_f32_16x16x32_f16(pf[kf], vf, o[df], 0, 0, 0);
      }

    __syncthreads();
  }

  float inv[4];
#pragma unroll
  for (int r = 0; r < 4; r++) {
    const float lq = __shfl(l_, (lane & 48) | (lg * 4 + r), 64);
    inv[r] = 1.0f / lq;
  }
  f16* cb = ctx + ((size_t)(b * SEQ + q0) * NH + h) * HD;
#pragma unroll
  for (int df = 0; df < 8; df++)
#pragma unroll
    for (int r = 0; r < 4; r++)
      cb[(size_t)(lg * 4 + r) * (NH * HD) + df * 16 + ll] = (f16)(o[df][r] * inv[r]);
}

extern "C" void kernel_launch(void* const* d_in, const int* in_sizes, int n_in,
                              void* d_out, int out_size, void* d_ws, size_t ws_size,
                              hipStream_t stream) {
  (void)in_sizes; (void)n_in; (void)out_size;
  const float* x  = (const float*)d_in[0];
  const float* wq = (const float*)d_in[1];
  const float* wk = (const float*)d_in[2];
  const float* wv = (const float*)d_in[3];
  const float* wo = (const float*)d_in[4];
  float* out = (float*)d_out;

  const size_t SZ_X  = (size_t)MTOK * DMODEL * sizeof(f16);
  const size_t SZ_KV = (size_t)MTOK * NKV * HD * sizeof(f16);
  if (ws_size < 3 * SZ_X + 2 * SZ_KV) return;

  char* ws = (char*)d_ws;
  f16* xh  = (f16*)ws;                      // x f16; reused as ctx
  f16* wT  = (f16*)(ws + SZ_X);             // transposed weight (wq -> wk|wv -> wo)
  f16* Qb  = (f16*)(ws + 2 * SZ_X);
  f16* Kb  = (f16*)(ws + 3 * SZ_X);         // [B,S,NKV,HD]
  f16* VTb = (f16*)(ws + 3 * SZ_X + SZ_KV); // [B,NKV,HD,S]

  const float KSC2 = 0.08838834764831845f * 1.4426950408889634f;  // 1/sqrt(128)*log2(e)

  cvt_f32_f16_k<<<dim3(MTOK * DMODEL / 8 / 256), 256, 0, stream>>>(x, xh, MTOK * DMODEL / 8);

  // Q projection (wq prescaled -> attn needs no Q prescale)
  transpose_cvt_k<<<dim3(DMODEL / 32, DMODEL / 32), 256, 0, stream>>>(wq, wT, DMODEL, DMODEL, KSC2);
  gemm256_k<0><<<dim3((MTOK / 256) * (DMODEL / 256)), 512, 0, stream>>>(xh, wT, Qb, MTOK, DMODEL, DMODEL);

  // merged K|V projection (8-phase BM128xBN256): wT rows 0-1023 = wk^T, rows 1024-2047 = wv^T
  transpose_cvt2_k<<<dim3(NKV * HD / 32, DMODEL / 32, 2), 256, 0, stream>>>(wk, wv, wT, DMODEL, NKV * HD);
  gemm_kv8_k<<<dim3((MTOK / 128) * (2048 / 256)), 512, 0, stream>>>(xh, wT, Kb, VTb, MTOK, 2048, DMODEL);

  attn_k9<<<dim3(BATCH * NKV * (SEQ / 32)), 512, 0, stream>>>(Qb, Kb, VTb, xh);

  transpose_cvt_k<<<dim3(DMODEL / 32, DMODEL / 32), 256, 0, stream>>>(wo, wT, DMODEL, DMODEL, 1.0f);
  gemm256_k<2><<<dim3((MTOK / 256) * (DMODEL / 256)), 512, 0, stream>>>(xh, wT, out, MTOK, DMODEL, DMODEL);
}

// Round 10
// 526.251 us; speedup vs baseline: 1.0522x; 1.0174x over previous
//
#include <hip/hip_runtime.h>
#include <math.h>

typedef _Float16 f16;
using f16x8 = __attribute__((ext_vector_type(8))) _Float16;
using f32x4 = __attribute__((ext_vector_type(4))) float;

#define BATCH 2
#define SEQ   2048
#define DMODEL 4096
#define NH    32
#define NKV   8
#define HD    128
#define MTOK  (BATCH*SEQ)

// ------------- fused prep: x f32->f16 convert (bid<8192) + wq transpose-scaled (bid>=8192) -------------
__global__ __launch_bounds__(256) void prep1_k(const float* __restrict__ x, f16* __restrict__ xh,
                                               const float* __restrict__ wq, f16* __restrict__ wqT,
                                               float scale) {
  __shared__ float tile[32][33];
  const int bid = blockIdx.x, t = threadIdx.x;
  if (bid < 8192) {
    const int i = bid * 256 + t;   // 8192*256 = MTOK*DMODEL/8 exactly
    const float4* p = reinterpret_cast<const float4*>(x) + (size_t)i * 2;
    float4 a = p[0], b = p[1];
    f16x8 o = { (f16)a.x, (f16)a.y, (f16)a.z, (f16)a.w,
                (f16)b.x, (f16)b.y, (f16)b.z, (f16)b.w };
    reinterpret_cast<f16x8*>(xh)[i] = o;
  } else {
    const int bb = bid - 8192;
    const int n0 = (bb & 127) * 32, k0 = (bb >> 7) * 32;
    const int r = t >> 3, c4 = (t & 7) << 2;
    const float4 v = *reinterpret_cast<const float4*>(wq + (size_t)(k0 + r) * DMODEL + n0 + c4);
    tile[r][c4 + 0] = v.x; tile[r][c4 + 1] = v.y; tile[r][c4 + 2] = v.z; tile[r][c4 + 3] = v.w;
    __syncthreads();
    union { f16 h[4]; ushort4 u4; } pk;
    pk.h[0] = (f16)(tile[c4 + 0][r] * scale);
    pk.h[1] = (f16)(tile[c4 + 1][r] * scale);
    pk.h[2] = (f16)(tile[c4 + 2][r] * scale);
    pk.h[3] = (f16)(tile[c4 + 3][r] * scale);
    *reinterpret_cast<ushort4*>(wqT + (size_t)(n0 + r) * DMODEL + k0 + c4) = pk.u4;
  }
}

// ------------- w[K][N] f32 -> wT[N][K] f16 -------------
__global__ __launch_bounds__(256) void transpose_cvt_k(const float* __restrict__ w,
                                                       f16* __restrict__ wt, int Kd, int Nd,
                                                       float scale) {
  __shared__ float tile[32][33];
  const int t = threadIdx.x;
  const int n0 = blockIdx.x * 32, k0 = blockIdx.y * 32;
  const int r = t >> 3, c4 = (t & 7) << 2;
  const float4 v = *reinterpret_cast<const float4*>(w + (size_t)(k0 + r) * Nd + n0 + c4);
  tile[r][c4 + 0] = v.x; tile[r][c4 + 1] = v.y; tile[r][c4 + 2] = v.z; tile[r][c4 + 3] = v.w;
  __syncthreads();
  union { f16 h[4]; ushort4 u4; } pk;
  pk.h[0] = (f16)(tile[c4 + 0][r] * scale);
  pk.h[1] = (f16)(tile[c4 + 1][r] * scale);
  pk.h[2] = (f16)(tile[c4 + 2][r] * scale);
  pk.h[3] = (f16)(tile[c4 + 3][r] * scale);
  *reinterpret_cast<ushort4*>(wt + (size_t)(n0 + r) * Kd + k0 + c4) = pk.u4;
}

// ------------- merged wk|wv transpose -------------
__global__ __launch_bounds__(256) void transpose_cvt2_k(const float* __restrict__ w0,
                                                        const float* __restrict__ w1,
                                                        f16* __restrict__ wt, int Kd, int Nd) {
  __shared__ float tile[32][33];
  const float* w = blockIdx.z ? w1 : w0;
  f16* dst = wt + (size_t)blockIdx.z * Nd * Kd;
  const int t = threadIdx.x;
  const int n0 = blockIdx.x * 32, k0 = blockIdx.y * 32;
  const int r = t >> 3, c4 = (t & 7) << 2;
  const float4 v = *reinterpret_cast<const float4*>(w + (size_t)(k0 + r) * Nd + n0 + c4);
  tile[r][c4 + 0] = v.x; tile[r][c4 + 1] = v.y; tile[r][c4 + 2] = v.z; tile[r][c4 + 3] = v.w;
  __syncthreads();
  union { f16 h[4]; ushort4 u4; } pk;
  pk.h[0] = (f16)tile[c4 + 0][r];
  pk.h[1] = (f16)tile[c4 + 1][r];
  pk.h[2] = (f16)tile[c4 + 2][r];
  pk.h[3] = (f16)tile[c4 + 3][r];
  *reinterpret_cast<ushort4*>(dst + (size_t)(n0 + r) * Kd + k0 + c4) = pk.u4;
}

// ------------- 8-phase KV projection GEMM: BM=128, BN=256 (grid 256 = 1/CU) -------------
__global__ __launch_bounds__(512, 2) void gemm_kv8_k(const f16* __restrict__ A,
                                                     const f16* __restrict__ BT,
                                                     f16* __restrict__ Kc,
                                                     f16* __restrict__ Vt,
                                                     int M, int N, int K) {
  __shared__ f16 lds[2 * 24576];   // 96 KB: per buf {A0 8K, A1 8K, B0 16K, B1 16K}
  char* ldsb = (char*)lds;

  const int t = threadIdx.x, lane = t & 63, w = t >> 6;
  const int wm = w >> 2, wn = w & 3;
  const int ll = lane & 15, lg = lane >> 4;
  const int nbn = N >> 8;
  const int nwg = gridDim.x, cpx = nwg >> 3, bid = blockIdx.x;
  const int swz = (bid & 7) * cpx + (bid >> 3);
  const int bm = swz / nbn, bn = swz % nbn;
  const size_t m0 = (size_t)bm << 7, n0 = (size_t)bn << 8;
  const int NT = K >> 6;

  const int uoff[4] = {0, 8192, 16384, 32768};

  auto stage = [&](int bufI, int unit, int ktS) {
    char* dstb = ldsb + (size_t)bufI * 49152 + uoff[unit];
    if (unit < 2) {
      const f16* base = A + (m0 + (size_t)(unit & 1) * 64) * (size_t)K;
      const int row = t >> 3, lin = t & 7;
      const int slot = lin ^ (row & 7);
      const f16* src = base + (size_t)row * K + ktS + slot * 8;
      __builtin_amdgcn_global_load_lds((const __attribute__((address_space(1))) void*)src,
          (__attribute__((address_space(3))) void*)(dstb + (size_t)t * 16), 16, 0, 0);
    } else {
      const f16* base = BT + (n0 + (size_t)(unit & 1) * 128) * (size_t)K;
#pragma unroll
      for (int rr = 0; rr < 2; rr++) {
        const int u = t + rr * 512;
        const int row = u >> 3, lin = u & 7;
        const int slot = lin ^ (row & 7);
        const f16* src = base + (size_t)row * K + ktS + slot * 8;
        __builtin_amdgcn_global_load_lds((const __attribute__((address_space(1))) void*)src,
            (__attribute__((address_space(3))) void*)(dstb + (size_t)u * 16), 16, 0, 0);
      }
    }
  };

  f32x4 acc[4][4];
#pragma unroll
  for (int i = 0; i < 4; i++)
#pragma unroll
    for (int j = 0; j < 4; j++) acc[i][j] = f32x4{0.f, 0.f, 0.f, 0.f};

  f16x8 af[2][2];
  f16x8 bfr[2][2][2];

  stage(0, 0, 0); stage(0, 1, 0); stage(0, 2, 0); stage(0, 3, 0);
  stage(1, 0, 64); stage(1, 2, 64); stage(1, 3, 64);
  asm volatile("s_waitcnt vmcnt(5)" ::: "memory");
  __builtin_amdgcn_sched_barrier(0);
  __builtin_amdgcn_s_barrier();

#define PHK(RBUF, RDA, RDB, SBUF, SUNIT, STILE, VM, MH, NHQ) do {                         \
    if ((RDA) >= 0) {                                                                     \
      const char* ab = ldsb + (size_t)(RBUF) * 49152 + uoff[MH];                          \
      _Pragma("unroll") for (int mi2 = 0; mi2 < 2; mi2++)                                 \
        _Pragma("unroll") for (int kk = 0; kk < 2; kk++) {                                \
          const int ri = wm * 32 + mi2 * 16 + ll;                                         \
          af[mi2][kk] = *reinterpret_cast<const f16x8*>(ab + ri * 128                     \
                               + ((((kk << 2) + lg) ^ (ri & 7)) << 4));                   \
        }                                                                                 \
    }                                                                                     \
    if ((RDB) >= 0) {                                                                     \
      const char* bb = ldsb + (size_t)(RBUF) * 49152 + uoff[2 + (RDB)];                   \
      _Pragma("unroll") for (int ni2 = 0; ni2 < 2; ni2++)                                 \
        _Pragma("unroll") for (int kk = 0; kk < 2; kk++) {                                \
          const int ri = wn * 32 + ni2 * 16 + ll;                                         \
          bfr[RDB][ni2][kk] = *reinterpret_cast<const f16x8*>(bb + ri * 128               \
                               + ((((kk << 2) + lg) ^ (ri & 7)) << 4));                   \
        }                                                                                 \
    }                                                                                     \
    stage((SBUF), (SUNIT), ((STILE) & (NT - 1)) << 6);                                    \
    if (VM) { asm volatile("s_waitcnt vmcnt(5)" ::: "memory");                            \
              __builtin_amdgcn_sched_barrier(0); }                                        \
    __builtin_amdgcn_s_barrier();                                                         \
    asm volatile("s_waitcnt lgkmcnt(0)" ::: "memory");                                    \
    __builtin_amdgcn_sched_barrier(0);                                                    \
    __builtin_amdgcn_s_setprio(1);                                                        \
    _Pragma("unroll") for (int kk = 0; kk < 2; kk++)                                      \
      _Pragma("unroll") for (int mi2 = 0; mi2 < 2; mi2++)                                 \
        _Pragma("unroll") for (int ni2 = 0; ni2 < 2; ni2++)                               \
          acc[(MH) * 2 + mi2][(NHQ) * 2 + ni2] = __builtin_amdgcn_mfma_f32_16x16x32_f16(  \
              af[mi2][kk], bfr[NHQ][ni2][kk], acc[(MH) * 2 + mi2][(NHQ) * 2 + ni2],       \
              0, 0, 0);                                                                   \
    __builtin_amdgcn_s_setprio(0);                                                        \
    __builtin_amdgcn_s_barrier();                                                         \
  } while (0)

  for (int tt = 0; tt < NT; tt += 2) {
    PHK(0,  0,  0, 1, 1, tt + 1, false, 0, 0);
    PHK(0, -1,  1, 0, 0, tt + 2, false, 0, 1);
    PHK(0,  1, -1, 0, 2, tt + 2, false, 1, 0);
    PHK(0, -1, -1, 0, 3, tt + 2, true , 1, 1);
    PHK(1,  0,  0, 0, 1, tt + 2, false, 0, 0);
    PHK(1, -1,  1, 1, 0, tt + 3, false, 0, 1);
    PHK(1,  1, -1, 1, 2, tt + 3, false, 1, 0);
    PHK(1, -1, -1, 1, 3, tt + 3, true , 1, 1);
  }
#undef PHK

#pragma unroll
  for (int mh = 0; mh < 2; mh++)
#pragma unroll
    for (int mi2 = 0; mi2 < 2; mi2++) {
      const size_t r0 = m0 + mh * 64 + wm * 32 + mi2 * 16 + lg * 4;
#pragma unroll
      for (int nh = 0; nh < 2; nh++)
#pragma unroll
        for (int ni2 = 0; ni2 < 2; ni2++) {
          const size_t c = n0 + nh * 128 + wn * 32 + ni2 * 16 + ll;
          const f32x4 v = acc[mh * 2 + mi2][nh * 2 + ni2];
          if ((int)c < 1024) {
#pragma unroll
            for (int rr = 0; rr < 4; rr++) Kc[(r0 + rr) * 1024 + c] = (f16)v[rr];
          } else {
            const int nc = (int)c - 1024;
            const int kvh = nc >> 7, d = nc & 127;
            const int b = (int)(r0 >> 11), sc = (int)(r0 & 2047);
            union { f16 h[4]; ushort4 u4; } pk;
#pragma unroll
            for (int rr = 0; rr < 4; rr++) pk.h[rr] = (f16)v[rr];
            *reinterpret_cast<ushort4*>(Vt + (((size_t)(b * NKV + kvh) * HD + d) * SEQ + sc)) = pk.u4;
          }
        }
    }
}

// ------------- 256^2 8-phase GEMM (T2+T3+T4+T5) for the two 4096^3 GEMMs -------------
template<int MODE>
__global__ __launch_bounds__(512, 2) void gemm256_k(const f16* __restrict__ A,
                                                    const f16* __restrict__ BT,
                                                    void* __restrict__ Cv,
                                                    int M, int N, int K) {
  __shared__ f16 lds[2 * 4 * 128 * 64];   // 128 KB
  char* ldsb = (char*)lds;

  const int t = threadIdx.x, lane = t & 63, w = t >> 6;
  const int wm = w >> 2, wn = w & 3;
  const int ll = lane & 15, lg = lane >> 4;
  const int nbn = N >> 8;
  const int nwg = gridDim.x, cpx = nwg >> 3, bid = blockIdx.x;
  const int swz = (bid & 7) * cpx + (bid >> 3);
  const int bm = swz / nbn, bn = swz % nbn;
  const size_t m0 = (size_t)bm << 8, n0 = (size_t)bn << 8;
  const int NT = K >> 6;

  auto stage = [&](int bufI, int unit, int ktS) {
    const f16* base = (unit < 2) ? (A + (m0 + (size_t)(unit & 1) * 128) * (size_t)K)
                                 : (BT + (n0 + (size_t)(unit & 1) * 128) * (size_t)K);
#pragma unroll
    for (int rr = 0; rr < 2; rr++) {
      const int u = t + rr * 512;
      const int row = u >> 3, lin = u & 7;
      const int slot = lin ^ (row & 7);
      const f16* src = base + (size_t)row * K + ktS + slot * 8;
      char* dst = ldsb + (size_t)(bufI * 4 + unit) * 16384 + (size_t)(w * 64 + rr * 512) * 16;
      __builtin_amdgcn_global_load_lds((const __attribute__((address_space(1))) void*)src,
          (__attribute__((address_space(3))) void*)dst, 16, 0, 0);
    }
  };

  f32x4 acc[8][4];
#pragma unroll
  for (int i = 0; i < 8; i++)
#pragma unroll
    for (int j = 0; j < 4; j++) acc[i][j] = f32x4{0.f, 0.f, 0.f, 0.f};

  f16x8 af[4][2];
  f16x8 bfr[2][2][2];

  stage(0, 0, 0); stage(0, 2, 0); stage(0, 3, 0); stage(0, 1, 0);
  stage(1, 0, 64); stage(1, 2, 64); stage(1, 3, 64);
  asm volatile("s_waitcnt vmcnt(6)" ::: "memory");
  __builtin_amdgcn_sched_barrier(0);
  __builtin_amdgcn_s_barrier();

#define PH(RBUF, RDA, RDB, SBUF, SUNIT, STILE, VM, MH, NHQ) do {                          \
    if ((RDA) >= 0) {                                                                     \
      const char* ab = ldsb + (size_t)((RBUF) * 4 + (RDA)) * 16384;                       \
      _Pragma("unroll") for (int mi = 0; mi < 4; mi++)                                    \
        _Pragma("unroll") for (int kk = 0; kk < 2; kk++)                                  \
          af[mi][kk] = *reinterpret_cast<const f16x8*>(ab + (mi * 32 + wm * 16 + ll) * 128\
                               + ((((kk << 2) + lg) ^ (ll & 7)) << 4));                   \
    }                                                                                     \
    if ((RDB) >= 0) {                                                                     \
      const char* bb = ldsb + (size_t)((RBUF) * 4 + 2 + (RDB)) * 16384;                   \
      _Pragma("unroll") for (int ni = 0; ni < 2; ni++)                                    \
        _Pragma("unroll") for (int kk = 0; kk < 2; kk++)                                  \
          bfr[RDB][ni][kk] = *reinterpret_cast<const f16x8*>(bb +                         \
                               (wn * 32 + ni * 16 + ll) * 128                             \
                               + ((((kk << 2) + lg) ^ (ll & 7)) << 4));                   \
    }                                                                                     \
    stage((SBUF), (SUNIT), ((STILE) & (NT - 1)) << 6);                                    \
    if (VM) { asm volatile("s_waitcnt vmcnt(6)" ::: "memory");                            \
              __builtin_amdgcn_sched_barrier(0); }                                        \
    __builtin_amdgcn_s_barrier();                                                         \
    asm volatile("s_waitcnt lgkmcnt(0)" ::: "memory");                                    \
    __builtin_amdgcn_sched_barrier(0);                                                    \
    __builtin_amdgcn_s_setprio(1);                                                        \
    _Pragma("unroll") for (int kk = 0; kk < 2; kk++)                                      \
      _Pragma("unroll") for (int mi = 0; mi < 4; mi++)                                    \
        _Pragma("unroll") for (int ni = 0; ni < 2; ni++)                                  \
          acc[(MH) * 4 + mi][(NHQ) * 2 + ni] = __builtin_amdgcn_mfma_f32_16x16x32_f16(    \
              af[mi][kk], bfr[NHQ][ni][kk], acc[(MH) * 4 + mi][(NHQ) * 2 + ni], 0, 0, 0); \
    __builtin_amdgcn_s_setprio(0);                                                        \
    __builtin_amdgcn_s_barrier();                                                         \
  } while (0)

  for (int tt = 0; tt < NT; tt += 2) {
    PH(0,  0,  0, 1, 1, tt + 1, false, 0, 0);
    PH(0, -1,  1, 0, 0, tt + 2, false, 0, 1);
    PH(0,  1, -1, 0, 2, tt + 2, false, 1, 0);
    PH(0, -1, -1, 0, 3, tt + 2, true , 1, 1);
    PH(1,  0,  0, 0, 1, tt + 2, false, 0, 0);
    PH(1, -1,  1, 1, 0, tt + 3, false, 0, 1);
    PH(1,  1, -1, 1, 2, tt + 3, false, 1, 0);
    PH(1, -1, -1, 1, 3, tt + 3, true , 1, 1);
  }
#undef PH

#pragma unroll
  for (int mh = 0; mh < 2; mh++)
#pragma unroll
    for (int mi = 0; mi < 4; mi++) {
      const size_t r0 = m0 + mh * 128 + mi * 32 + wm * 16 + lg * 4;
#pragma unroll
      for (int nh = 0; nh < 2; nh++)
#pragma unroll
        for (int ni = 0; ni < 2; ni++) {
          const size_t c = n0 + nh * 128 + wn * 32 + ni * 16 + ll;
          const f32x4 v = acc[mh * 4 + mi][nh * 2 + ni];
          if (MODE == 0) {
            f16* C = (f16*)Cv;
#pragma unroll
            for (int rr = 0; rr < 4; rr++) C[(r0 + rr) * N + c] = (f16)v[rr];
          } else {
            float* C = (float*)Cv;
#pragma unroll
            for (int rr = 0; rr < 4; rr++) C[(r0 + rr) * N + c] = v[rr];
          }
        }
    }
}

// ------------- flash attention v10 = v7 + T5 setprio around MFMA clusters -------------
__global__ __launch_bounds__(512) void attn_k10(const f16* __restrict__ Q,
                                                const f16* __restrict__ Kb,
                                                const f16* __restrict__ VT,
                                                f16* __restrict__ ctx) {
  __shared__ f16 Klds[2][64 * 128];   // 16 KB x2
  __shared__ f16 Vlds[2][128 * 64];   // 16 KB x2
  __shared__ f16 Plds[8][16 * 64];    // 2 KB/wave (total 80 KB)

  const int t = threadIdx.x, lane = t & 63, w = t >> 6;
  const int bid = blockIdx.x;
  const int swz = (bid & 7) * 128 + (bid >> 3);
  const int qt = swz & 63, kvh = (swz >> 6) & 7, b = swz >> 9;
  const int h = kvh * 4 + (w & 3);
  const int q0 = qt * 32 + (w >> 2) * 16;
  const int ll = lane & 15, lg = lane >> 4;

  const f16* Qb = Q + ((size_t)(b * SEQ + q0) * NH + h) * HD;
  const f16* Kh = Kb + ((size_t)b * SEQ * NKV + kvh) * HD;
  const f16* Vh = VT + ((size_t)(b * NKV + kvh)) * HD * SEQ;

  f16x8 qf[4];
#pragma unroll
  for (int kd = 0; kd < 4; kd++)
    qf[kd] = *reinterpret_cast<const f16x8*>(Qb + (size_t)ll * (NH * HD) + kd * 32 + lg * 8);

  float m_ = -INFINITY;
  float l_ = 0.f;
  f32x4 o[8];
#pragma unroll
  for (int df = 0; df < 8; df++) o[df] = f32x4{0.f, 0.f, 0.f, 0.f};

  const float THR = 11.5416f;  // 8 nats in log2 units

  auto stage = [&](int bufi, int kt) {
#pragma unroll
    for (int rr = 0; rr < 2; rr++) {
      const int u = w * 128 + rr * 64 + lane;
      const int krow = u >> 4, klin = u & 15;
      const int kslot = klin ^ (krow & 7);
      const f16* ksrc = Kh + (size_t)(kt + krow) * (NKV * HD) + kslot * 8;
      __builtin_amdgcn_global_load_lds((const __attribute__((address_space(1))) void*)ksrc,
          (__attribute__((address_space(3))) void*)((char*)&Klds[bufi][0] + (size_t)u * 16), 16, 0, 0);
      const int vrow = u >> 3, vlin = u & 7;
      const int vslot = vlin ^ (vrow & 7);
      const f16* vsrc = Vh + (size_t)vrow * SEQ + kt + vslot * 8;
      __builtin_amdgcn_global_load_lds((const __attribute__((address_space(1))) void*)vsrc,
          (__attribute__((address_space(3))) void*)((char*)&Vlds[bufi][0] + (size_t)u * 16), 16, 0, 0);
    }
  };

  stage(0, 0);
  __syncthreads();

  for (int kt = 0; kt < SEQ; kt += 64) {
    const int buf = (kt >> 6) & 1;
    if (kt + 64 < SEQ) stage(buf ^ 1, kt + 64);

    const char* Kt = (const char*)Klds[buf];
    const char* Vt = (const char*)Vlds[buf];

    // S^T = K @ Q^T (setprio: favor MFMA-issuing wave while others stage/softmax)
    f32x4 s[4];
    __builtin_amdgcn_s_setprio(1);
#pragma unroll
    for (int nf = 0; nf < 4; nf++) {
      f32x4 a = f32x4{0.f, 0.f, 0.f, 0.f};
#pragma unroll
      for (int kd = 0; kd < 4; kd++) {
        const int row = nf * 16 + ll;
        f16x8 kf = *reinterpret_cast<const f16x8*>(
            Kt + row * 256 + ((((kd << 2) + lg) ^ (row & 7)) << 4));
        a = __builtin_amdgcn_mfma_f32_16x16x32_f16(kf, qf[kd], a, 0, 0, 0);
      }
      s[nf] = a;
    }
    __builtin_amdgcn_s_setprio(0);

    float mx = s[0][0];
#pragma unroll
    for (int nf = 0; nf < 4; nf++)
#pragma unroll
      for (int r = 0; r < 4; r++) mx = fmaxf(mx, s[nf][r]);

    if (!__all((int)(mx <= m_ + THR))) {
      float mr = fmaxf(mx, __shfl_xor(mx, 16, 64));
      mr = fmaxf(mr, __shfl_xor(mr, 32, 64));
      const float mn = fmaxf(m_, mr);
      const float corrq = __builtin_amdgcn_exp2f(m_ - mn);
      m_ = mn;
      l_ *= corrq;
#pragma unroll
      for (int r = 0; r < 4; r++) {
        const float c = __shfl(corrq, (lane & 48) | (lg * 4 + r), 64);
#pragma unroll
        for (int df = 0; df < 8; df++) o[df][r] *= c;
      }
    }

    float rs = 0.f;
#pragma unroll
    for (int nf = 0; nf < 4; nf++)
#pragma unroll
      for (int r = 0; r < 4; r++) {
        const float p = __builtin_amdgcn_exp2f(s[nf][r] - m_);
        s[nf][r] = p;
        rs += p;
      }
    rs += __shfl_xor(rs, 16, 64);
    rs += __shfl_xor(rs, 32, 64);
    l_ += rs;

    char* Pw = (char*)&Plds[w][0];
#pragma unroll
    for (int nf = 0; nf < 4; nf++) {
      union { f16 h[4]; ushort4 u4; } pk;
#pragma unroll
      for (int r = 0; r < 4; r++) pk.h[r] = (f16)s[nf][r];
      *reinterpret_cast<ushort4*>(Pw + ll * 128 + ((nf * 32 + lg * 8) ^ ((ll & 7) << 4))) = pk.u4;
    }

    f16x8 pf[2];
#pragma unroll
    for (int kf = 0; kf < 2; kf++)
      pf[kf] = *reinterpret_cast<const f16x8*>(Pw + ll * 128 + (((kf << 6) + (lg << 4)) ^ ((ll & 7) << 4)));

    __builtin_amdgcn_s_setprio(1);
#pragma unroll
    for (int kf = 0; kf < 2; kf++)
#pragma unroll
      for (int df = 0; df < 8; df++) {
        const int row = df * 16 + ll;
        f16x8 vf = *reinterpret_cast<const f16x8*>(
            Vt + row * 128 + ((((kf << 2) + lg) ^ (row & 7)) << 4));
        o[df] = __builtin_amdgcn_mfma_f32_16x16x32_f16(pf[kf], vf, o[df], 0, 0, 0);
      }
    __builtin_amdgcn_s_setprio(0);

    __syncthreads();
  }

  float inv[4];
#pragma unroll
  for (int r = 0; r < 4; r++) {
    const float lq = __shfl(l_, (lane & 48) | (lg * 4 + r), 64);
    inv[r] = 1.0f / lq;
  }
  f16* cb = ctx + ((size_t)(b * SEQ + q0) * NH + h) * HD;
#pragma unroll
  for (int df = 0; df < 8; df++)
#pragma unroll
    for (int r = 0; r < 4; r++)
      cb[(size_t)(lg * 4 + r) * (NH * HD) + df * 16 + ll] = (f16)(o[df][r] * inv[r]);
}

extern "C" void kernel_launch(void* const* d_in, const int* in_sizes, int n_in,
                              void* d_out, int out_size, void* d_ws, size_t ws_size,
                              hipStream_t stream) {
  (void)in_sizes; (void)n_in; (void)out_size;
  const float* x  = (const float*)d_in[0];
  const float* wq = (const float*)d_in[1];
  const float* wk = (const float*)d_in[2];
  const float* wv = (const float*)d_in[3];
  const float* wo = (const float*)d_in[4];
  float* out = (float*)d_out;

  const size_t SZ_X  = (size_t)MTOK * DMODEL * sizeof(f16);
  const size_t SZ_KV = (size_t)MTOK * NKV * HD * sizeof(f16);
  if (ws_size < 3 * SZ_X + 2 * SZ_KV) return;

  char* ws = (char*)d_ws;
  f16* xh  = (f16*)ws;                      // x f16; reused as ctx
  f16* wT  = (f16*)(ws + SZ_X);             // transposed weight (wq -> wk|wv -> wo)
  f16* Qb  = (f16*)(ws + 2 * SZ_X);
  f16* Kb  = (f16*)(ws + 3 * SZ_X);         // [B,S,NKV,HD]
  f16* VTb = (f16*)(ws + 3 * SZ_X + SZ_KV); // [B,NKV,HD,S]

  const float KSC2 = 0.08838834764831845f * 1.4426950408889634f;  // 1/sqrt(128)*log2(e)

  // fused: x convert + wq transpose (prescaled)
  prep1_k<<<dim3(8192 + 16384), 256, 0, stream>>>(x, xh, wq, wT, KSC2);
  gemm256_k<0><<<dim3((MTOK / 256) * (DMODEL / 256)), 512, 0, stream>>>(xh, wT, Qb, MTOK, DMODEL, DMODEL);

  // merged K|V projection (8-phase BM128xBN256)
  transpose_cvt2_k<<<dim3(NKV * HD / 32, DMODEL / 32, 2), 256, 0, stream>>>(wk, wv, wT, DMODEL, NKV * HD);
  gemm_kv8_k<<<dim3((MTOK / 128) * (2048 / 256)), 512, 0, stream>>>(xh, wT, Kb, VTb, MTOK, 2048, DMODEL);

  attn_k10<<<dim3(BATCH * NKV * (SEQ / 32)), 512, 0, stream>>>(Qb, Kb, VTb, xh);

  transpose_cvt_k<<<dim3(DMODEL / 32, DMODEL / 32), 256, 0, stream>>>(wo, wT, DMODEL, DMODEL, 1.0f);
  gemm256_k<2><<<dim3((MTOK / 256) * (DMODEL / 256)), 512, 0, stream>>>(xh, wT, out, MTOK, DMODEL, DMODEL);
}

// Round 11
// 522.161 us; speedup vs baseline: 1.0605x; 1.0078x over previous
//
#include <hip/hip_runtime.h>
#include <math.h>

typedef _Float16 f16;
using f16x8 = __attribute__((ext_vector_type(8))) _Float16;
using f32x4 = __attribute__((ext_vector_type(4))) float;

#define BATCH 2
#define SEQ   2048
#define DMODEL 4096
#define NH    32
#define NKV   8
#define HD    128
#define MTOK  (BATCH*SEQ)

// ------------- fused prep: block-role by bid range -------------
// [0,8192): x f32->f16 ; [8192,24576): wq^T (scaled) -> wqT ; [24576,32768): wk|wv^T -> wkvT ;
// [32768,49152): wo^T -> woT. Grid size selects how many roles run.
__global__ __launch_bounds__(256) void prep_k(const float* __restrict__ x, f16* __restrict__ xh,
                                              const float* __restrict__ wq, f16* __restrict__ wqT,
                                              const float* __restrict__ wk, const float* __restrict__ wv,
                                              f16* __restrict__ wkvT,
                                              const float* __restrict__ wo, f16* __restrict__ woT,
                                              float scale) {
  __shared__ float tile[32][33];
  const int bid = blockIdx.x, t = threadIdx.x;
  if (bid < 8192) {
    const int i = bid * 256 + t;   // 8192*256 = MTOK*DMODEL/8
    const float4* p = reinterpret_cast<const float4*>(x) + (size_t)i * 2;
    float4 a = p[0], b = p[1];
    f16x8 o = { (f16)a.x, (f16)a.y, (f16)a.z, (f16)a.w,
                (f16)b.x, (f16)b.y, (f16)b.z, (f16)b.w };
    reinterpret_cast<f16x8*>(xh)[i] = o;
    return;
  }
  const float* w; f16* dst; int Nd; float sc;
  int bb;
  if (bid < 24576)      { bb = bid - 8192;  w = wq; dst = wqT;  Nd = DMODEL; sc = scale; }
  else if (bid < 32768) { bb = bid - 24576; const int z = bb >> 12; bb &= 4095;
                          w = z ? wv : wk; dst = wkvT + (size_t)z * 1024 * DMODEL; Nd = 1024; sc = 1.0f; }
  else                  { bb = bid - 32768; w = wo; dst = woT; Nd = DMODEL; sc = 1.0f; }
  const int ntile = Nd >> 5;
  const int n0 = (bb % ntile) * 32, k0 = (bb / ntile) * 32;
  const int r = t >> 3, c4 = (t & 7) << 2;
  const float4 v = *reinterpret_cast<const float4*>(w + (size_t)(k0 + r) * Nd + n0 + c4);
  tile[r][c4 + 0] = v.x; tile[r][c4 + 1] = v.y; tile[r][c4 + 2] = v.z; tile[r][c4 + 3] = v.w;
  __syncthreads();
  union { f16 h[4]; ushort4 u4; } pk;
  pk.h[0] = (f16)(tile[c4 + 0][r] * sc);
  pk.h[1] = (f16)(tile[c4 + 1][r] * sc);
  pk.h[2] = (f16)(tile[c4 + 2][r] * sc);
  pk.h[3] = (f16)(tile[c4 + 3][r] * sc);
  *reinterpret_cast<ushort4*>(dst + (size_t)(n0 + r) * DMODEL + k0 + c4) = pk.u4;
}

// ------------- standalone transpose (fallback paths) -------------
__global__ __launch_bounds__(256) void transpose_cvt_k(const float* __restrict__ w,
                                                       f16* __restrict__ wt, int Kd, int Nd,
                                                       float scale) {
  __shared__ float tile[32][33];
  const int t = threadIdx.x;
  const int n0 = blockIdx.x * 32, k0 = blockIdx.y * 32;
  const int r = t >> 3, c4 = (t & 7) << 2;
  const float4 v = *reinterpret_cast<const float4*>(w + (size_t)(k0 + r) * Nd + n0 + c4);
  tile[r][c4 + 0] = v.x; tile[r][c4 + 1] = v.y; tile[r][c4 + 2] = v.z; tile[r][c4 + 3] = v.w;
  __syncthreads();
  union { f16 h[4]; ushort4 u4; } pk;
  pk.h[0] = (f16)(tile[c4 + 0][r] * scale);
  pk.h[1] = (f16)(tile[c4 + 1][r] * scale);
  pk.h[2] = (f16)(tile[c4 + 2][r] * scale);
  pk.h[3] = (f16)(tile[c4 + 3][r] * scale);
  *reinterpret_cast<ushort4*>(wt + (size_t)(n0 + r) * Kd + k0 + c4) = pk.u4;
}

__global__ __launch_bounds__(256) void transpose_cvt2_k(const float* __restrict__ w0,
                                                        const float* __restrict__ w1,
                                                        f16* __restrict__ wt, int Kd, int Nd) {
  __shared__ float tile[32][33];
  const float* w = blockIdx.z ? w1 : w0;
  f16* dst = wt + (size_t)blockIdx.z * Nd * Kd;
  const int t = threadIdx.x;
  const int n0 = blockIdx.x * 32, k0 = blockIdx.y * 32;
  const int r = t >> 3, c4 = (t & 7) << 2;
  const float4 v = *reinterpret_cast<const float4*>(w + (size_t)(k0 + r) * Nd + n0 + c4);
  tile[r][c4 + 0] = v.x; tile[r][c4 + 1] = v.y; tile[r][c4 + 2] = v.z; tile[r][c4 + 3] = v.w;
  __syncthreads();
  union { f16 h[4]; ushort4 u4; } pk;
  pk.h[0] = (f16)tile[c4 + 0][r];
  pk.h[1] = (f16)tile[c4 + 1][r];
  pk.h[2] = (f16)tile[c4 + 2][r];
  pk.h[3] = (f16)tile[c4 + 3][r];
  *reinterpret_cast<ushort4*>(dst + (size_t)(n0 + r) * Kd + k0 + c4) = pk.u4;
}

__global__ __launch_bounds__(256) void cvt_f32_f16_k(const float* __restrict__ in,
                                                     f16* __restrict__ out, int n8) {
  int i = blockIdx.x * 256 + threadIdx.x;
  if (i >= n8) return;
  const float4* p = reinterpret_cast<const float4*>(in) + (size_t)i * 2;
  float4 a = p[0], b = p[1];
  f16x8 o = { (f16)a.x, (f16)a.y, (f16)a.z, (f16)a.w,
              (f16)b.x, (f16)b.y, (f16)b.z, (f16)b.w };
  reinterpret_cast<f16x8*>(out)[i] = o;
}

// ------------- 8-phase KV projection GEMM: BM=128, BN=256 (grid 256 = 1/CU) -------------
__global__ __launch_bounds__(512, 2) void gemm_kv8_k(const f16* __restrict__ A,
                                                     const f16* __restrict__ BT,
                                                     f16* __restrict__ Kc,
                                                     f16* __restrict__ Vt,
                                                     int M, int N, int K) {
  __shared__ f16 lds[2 * 24576];   // 96 KB
  char* ldsb = (char*)lds;

  const int t = threadIdx.x, lane = t & 63, w = t >> 6;
  const int wm = w >> 2, wn = w & 3;
  const int ll = lane & 15, lg = lane >> 4;
  const int nbn = N >> 8;
  const int nwg = gridDim.x, cpx = nwg >> 3, bid = blockIdx.x;
  const int swz = (bid & 7) * cpx + (bid >> 3);
  const int bm = swz / nbn, bn = swz % nbn;
  const size_t m0 = (size_t)bm << 7, n0 = (size_t)bn << 8;
  const int NT = K >> 6;

  const int uoff[4] = {0, 8192, 16384, 32768};

  auto stage = [&](int bufI, int unit, int ktS) {
    char* dstb = ldsb + (size_t)bufI * 49152 + uoff[unit];
    if (unit < 2) {
      const f16* base = A + (m0 + (size_t)(unit & 1) * 64) * (size_t)K;
      const int row = t >> 3, lin = t & 7;
      const int slot = lin ^ (row & 7);
      const f16* src = base + (size_t)row * K + ktS + slot * 8;
      __builtin_amdgcn_global_load_lds((const __attribute__((address_space(1))) void*)src,
          (__attribute__((address_space(3))) void*)(dstb + (size_t)t * 16), 16, 0, 0);
    } else {
      const f16* base = BT + (n0 + (size_t)(unit & 1) * 128) * (size_t)K;
#pragma unroll
      for (int rr = 0; rr < 2; rr++) {
        const int u = t + rr * 512;
        const int row = u >> 3, lin = u & 7;
        const int slot = lin ^ (row & 7);
        const f16* src = base + (size_t)row * K + ktS + slot * 8;
        __builtin_amdgcn_global_load_lds((const __attribute__((address_space(1))) void*)src,
            (__attribute__((address_space(3))) void*)(dstb + (size_t)u * 16), 16, 0, 0);
      }
    }
  };

  f32x4 acc[4][4];
#pragma unroll
  for (int i = 0; i < 4; i++)
#pragma unroll
    for (int j = 0; j < 4; j++) acc[i][j] = f32x4{0.f, 0.f, 0.f, 0.f};

  f16x8 af[2][2];
  f16x8 bfr[2][2][2];

  stage(0, 0, 0); stage(0, 1, 0); stage(0, 2, 0); stage(0, 3, 0);
  stage(1, 0, 64); stage(1, 2, 64); stage(1, 3, 64);
  asm volatile("s_waitcnt vmcnt(5)" ::: "memory");
  __builtin_amdgcn_sched_barrier(0);
  __builtin_amdgcn_s_barrier();

#define PHK(RBUF, RDA, RDB, SBUF, SUNIT, STILE, VM, MH, NHQ) do {                         \
    if ((RDA) >= 0) {                                                                     \
      const char* ab = ldsb + (size_t)(RBUF) * 49152 + uoff[MH];                          \
      _Pragma("unroll") for (int mi2 = 0; mi2 < 2; mi2++)                                 \
        _Pragma("unroll") for (int kk = 0; kk < 2; kk++) {                                \
          const int ri = wm * 32 + mi2 * 16 + ll;                                         \
          af[mi2][kk] = *reinterpret_cast<const f16x8*>(ab + ri * 128                     \
                               + ((((kk << 2) + lg) ^ (ri & 7)) << 4));                   \
        }                                                                                 \
    }                                                                                     \
    if ((RDB) >= 0) {                                                                     \
      const char* bb = ldsb + (size_t)(RBUF) * 49152 + uoff[2 + (RDB)];                   \
      _Pragma("unroll") for (int ni2 = 0; ni2 < 2; ni2++)                                 \
        _Pragma("unroll") for (int kk = 0; kk < 2; kk++) {                                \
          const int ri = wn * 32 + ni2 * 16 + ll;                                         \
          bfr[RDB][ni2][kk] = *reinterpret_cast<const f16x8*>(bb + ri * 128               \
                               + ((((kk << 2) + lg) ^ (ri & 7)) << 4));                   \
        }                                                                                 \
    }                                                                                     \
    stage((SBUF), (SUNIT), ((STILE) & (NT - 1)) << 6);                                    \
    if (VM) { asm volatile("s_waitcnt vmcnt(5)" ::: "memory");                            \
              __builtin_amdgcn_sched_barrier(0); }                                        \
    __builtin_amdgcn_s_barrier();                                                         \
    asm volatile("s_waitcnt lgkmcnt(0)" ::: "memory");                                    \
    __builtin_amdgcn_sched_barrier(0);                                                    \
    __builtin_amdgcn_s_setprio(1);                                                        \
    _Pragma("unroll") for (int kk = 0; kk < 2; kk++)                                      \
      _Pragma("unroll") for (int mi2 = 0; mi2 < 2; mi2++)                                 \
        _Pragma("unroll") for (int ni2 = 0; ni2 < 2; ni2++)                               \
          acc[(MH) * 2 + mi2][(NHQ) * 2 + ni2] = __builtin_amdgcn_mfma_f32_16x16x32_f16(  \
              af[mi2][kk], bfr[NHQ][ni2][kk], acc[(MH) * 2 + mi2][(NHQ) * 2 + ni2],       \
              0, 0, 0);                                                                   \
    __builtin_amdgcn_s_setprio(0);                                                        \
    __builtin_amdgcn_s_barrier();                                                         \
  } while (0)

  for (int tt = 0; tt < NT; tt += 2) {
    PHK(0,  0,  0, 1, 1, tt + 1, false, 0, 0);
    PHK(0, -1,  1, 0, 0, tt + 2, false, 0, 1);
    PHK(0,  1, -1, 0, 2, tt + 2, false, 1, 0);
    PHK(0, -1, -1, 0, 3, tt + 2, true , 1, 1);
    PHK(1,  0,  0, 0, 1, tt + 2, false, 0, 0);
    PHK(1, -1,  1, 1, 0, tt + 3, false, 0, 1);
    PHK(1,  1, -1, 1, 2, tt + 3, false, 1, 0);
    PHK(1, -1, -1, 1, 3, tt + 3, true , 1, 1);
  }
#undef PHK

#pragma unroll
  for (int mh = 0; mh < 2; mh++)
#pragma unroll
    for (int mi2 = 0; mi2 < 2; mi2++) {
      const size_t r0 = m0 + mh * 64 + wm * 32 + mi2 * 16 + lg * 4;
#pragma unroll
      for (int nh = 0; nh < 2; nh++)
#pragma unroll
        for (int ni2 = 0; ni2 < 2; ni2++) {
          const size_t c = n0 + nh * 128 + wn * 32 + ni2 * 16 + ll;
          const f32x4 v = acc[mh * 2 + mi2][nh * 2 + ni2];
          if ((int)c < 1024) {
#pragma unroll
            for (int rr = 0; rr < 4; rr++) Kc[(r0 + rr) * 1024 + c] = (f16)v[rr];
          } else {
            const int nc = (int)c - 1024;
            const int kvh = nc >> 7, d = nc & 127;
            const int b = (int)(r0 >> 11), sc = (int)(r0 & 2047);
            union { f16 h[4]; ushort4 u4; } pk;
#pragma unroll
            for (int rr = 0; rr < 4; rr++) pk.h[rr] = (f16)v[rr];
            *reinterpret_cast<ushort4*>(Vt + (((size_t)(b * NKV + kvh) * HD + d) * SEQ + sc)) = pk.u4;
          }
        }
    }
}

// ------------- 256^2 8-phase GEMM (T2+T3+T4+T5) + lgkm(8) hint on 12-read phases -------------
template<int MODE>
__global__ __launch_bounds__(512, 2) void gemm256_k(const f16* __restrict__ A,
                                                    const f16* __restrict__ BT,
                                                    void* __restrict__ Cv,
                                                    int M, int N, int K) {
  __shared__ f16 lds[2 * 4 * 128 * 64];   // 128 KB
  char* ldsb = (char*)lds;

  const int t = threadIdx.x, lane = t & 63, w = t >> 6;
  const int wm = w >> 2, wn = w & 3;
  const int ll = lane & 15, lg = lane >> 4;
  const int nbn = N >> 8;
  const int nwg = gridDim.x, cpx = nwg >> 3, bid = blockIdx.x;
  const int swz = (bid & 7) * cpx + (bid >> 3);
  const int bm = swz / nbn, bn = swz % nbn;
  const size_t m0 = (size_t)bm << 8, n0 = (size_t)bn << 8;
  const int NT = K >> 6;

  auto stage = [&](int bufI, int unit, int ktS) {
    const f16* base = (unit < 2) ? (A + (m0 + (size_t)(unit & 1) * 128) * (size_t)K)
                                 : (BT + (n0 + (size_t)(unit & 1) * 128) * (size_t)K);
#pragma unroll
    for (int rr = 0; rr < 2; rr++) {
      const int u = t + rr * 512;
      const int row = u >> 3, lin = u & 7;
      const int slot = lin ^ (row & 7);
      const f16* src = base + (size_t)row * K + ktS + slot * 8;
      char* dst = ldsb + (size_t)(bufI * 4 + unit) * 16384 + (size_t)(w * 64 + rr * 512) * 16;
      __builtin_amdgcn_global_load_lds((const __attribute__((address_space(1))) void*)src,
          (__attribute__((address_space(3))) void*)dst, 16, 0, 0);
    }
  };

  f32x4 acc[8][4];
#pragma unroll
  for (int i = 0; i < 8; i++)
#pragma unroll
    for (int j = 0; j < 4; j++) acc[i][j] = f32x4{0.f, 0.f, 0.f, 0.f};

  f16x8 af[4][2];
  f16x8 bfr[2][2][2];

  stage(0, 0, 0); stage(0, 2, 0); stage(0, 3, 0); stage(0, 1, 0);
  stage(1, 0, 64); stage(1, 2, 64); stage(1, 3, 64);
  asm volatile("s_waitcnt vmcnt(6)" ::: "memory");
  __builtin_amdgcn_sched_barrier(0);
  __builtin_amdgcn_s_barrier();

#define PH(RBUF, RDA, RDB, SBUF, SUNIT, STILE, VM, MH, NHQ) do {                          \
    if ((RDA) >= 0) {                                                                     \
      const char* ab = ldsb + (size_t)((RBUF) * 4 + (RDA)) * 16384;                       \
      _Pragma("unroll") for (int mi = 0; mi < 4; mi++)                                    \
        _Pragma("unroll") for (int kk = 0; kk < 2; kk++)                                  \
          af[mi][kk] = *reinterpret_cast<const f16x8*>(ab + (mi * 32 + wm * 16 + ll) * 128\
                               + ((((kk << 2) + lg) ^ (ll & 7)) << 4));                   \
    }                                                                                     \
    if ((RDB) >= 0) {                                                                     \
      const char* bb = ldsb + (size_t)((RBUF) * 4 + 2 + (RDB)) * 16384;                   \
      _Pragma("unroll") for (int ni = 0; ni < 2; ni++)                                    \
        _Pragma("unroll") for (int kk = 0; kk < 2; kk++)                                  \
          bfr[RDB][ni][kk] = *reinterpret_cast<const f16x8*>(bb +                         \
                               (wn * 32 + ni * 16 + ll) * 128                             \
                               + ((((kk << 2) + lg) ^ (ll & 7)) << 4));                   \
    }                                                                                     \
    stage((SBUF), (SUNIT), ((STILE) & (NT - 1)) << 6);                                    \
    if ((RDA) >= 0 && (RDB) >= 0)                                                         \
      asm volatile("s_waitcnt lgkmcnt(8)" ::: "memory");  /* m201 12-read-phase hint */   \
    if (VM) { asm volatile("s_waitcnt vmcnt(6)" ::: "memory");                            \
              __builtin_amdgcn_sched_barrier(0); }                                        \
    __builtin_amdgcn_s_barrier();                                                         \
    asm volatile("s_waitcnt lgkmcnt(0)" ::: "memory");                                    \
    __builtin_amdgcn_sched_barrier(0);                                                    \
    __builtin_amdgcn_s_setprio(1);                                                        \
    _Pragma("unroll") for (int kk = 0; kk < 2; kk++)                                      \
      _Pragma("unroll") for (int mi = 0; mi < 4; mi++)                                    \
        _Pragma("unroll") for (int ni = 0; ni < 2; ni++)                                  \
          acc[(MH) * 4 + mi][(NHQ) * 2 + ni] = __builtin_amdgcn_mfma_f32_16x16x32_f16(    \
              af[mi][kk], bfr[NHQ][ni][kk], acc[(MH) * 4 + mi][(NHQ) * 2 + ni], 0, 0, 0); \
    __builtin_amdgcn_s_setprio(0);                                                        \
    __builtin_amdgcn_s_barrier();                                                         \
  } while (0)

  for (int tt = 0; tt < NT; tt += 2) {
    PH(0,  0,  0, 1, 1, tt + 1, false, 0, 0);
    PH(0, -1,  1, 0, 0, tt + 2, false, 0, 1);
    PH(0,  1, -1, 0, 2, tt + 2, false, 1, 0);
    PH(0, -1, -1, 0, 3, tt + 2, true , 1, 1);
    PH(1,  0,  0, 0, 1, tt + 2, false, 0, 0);
    PH(1, -1,  1, 1, 0, tt + 3, false, 0, 1);
    PH(1,  1, -1, 1, 2, tt + 3, false, 1, 0);
    PH(1, -1, -1, 1, 3, tt + 3, true , 1, 1);
  }
#undef PH

#pragma unroll
  for (int mh = 0; mh < 2; mh++)
#pragma unroll
    for (int mi = 0; mi < 4; mi++) {
      const size_t r0 = m0 + mh * 128 + mi * 32 + wm * 16 + lg * 4;
#pragma unroll
      for (int nh = 0; nh < 2; nh++)
#pragma unroll
        for (int ni = 0; ni < 2; ni++) {
          const size_t c = n0 + nh * 128 + wn * 32 + ni * 16 + ll;
          const f32x4 v = acc[mh * 4 + mi][nh * 2 + ni];
          if (MODE == 0) {
            f16* C = (f16*)Cv;
#pragma unroll
            for (int rr = 0; rr < 4; rr++) C[(r0 + rr) * N + c] = (f16)v[rr];
          } else {
            float* C = (float*)Cv;
#pragma unroll
            for (int rr = 0; rr < 4; rr++) C[(r0 + rr) * N + c] = v[rr];
          }
        }
    }
}

// ------------- flash attention (round-10 proven: v7 + T5 setprio, 177.8 us) -------------
__global__ __launch_bounds__(512) void attn_k11(const f16* __restrict__ Q,
                                                const f16* __restrict__ Kb,
                                                const f16* __restrict__ VT,
                                                f16* __restrict__ ctx) {
  __shared__ f16 Klds[2][64 * 128];
  __shared__ f16 Vlds[2][128 * 64];
  __shared__ f16 Plds[8][16 * 64];

  const int t = threadIdx.x, lane = t & 63, w = t >> 6;
  const int bid = blockIdx.x;
  const int swz = (bid & 7) * 128 + (bid >> 3);
  const int qt = swz & 63, kvh = (swz >> 6) & 7, b = swz >> 9;
  const int h = kvh * 4 + (w & 3);
  const int q0 = qt * 32 + (w >> 2) * 16;
  const int ll = lane & 15, lg = lane >> 4;

  const f16* Qb = Q + ((size_t)(b * SEQ + q0) * NH + h) * HD;
  const f16* Kh = Kb + ((size_t)b * SEQ * NKV + kvh) * HD;
  const f16* Vh = VT + ((size_t)(b * NKV + kvh)) * HD * SEQ;

  f16x8 qf[4];
#pragma unroll
  for (int kd = 0; kd < 4; kd++)
    qf[kd] = *reinterpret_cast<const f16x8*>(Qb + (size_t)ll * (NH * HD) + kd * 32 + lg * 8);

  float m_ = -INFINITY;
  float l_ = 0.f;
  f32x4 o[8];
#pragma unroll
  for (int df = 0; df < 8; df++) o[df] = f32x4{0.f, 0.f, 0.f, 0.f};

  const float THR = 11.5416f;

  auto stage = [&](int bufi, int kt) {
#pragma unroll
    for (int rr = 0; rr < 2; rr++) {
      const int u = w * 128 + rr * 64 + lane;
      const int krow = u >> 4, klin = u & 15;
      const int kslot = klin ^ (krow & 7);
      const f16* ksrc = Kh + (size_t)(kt + krow) * (NKV * HD) + kslot * 8;
      __builtin_amdgcn_global_load_lds((const __attribute__((address_space(1))) void*)ksrc,
          (__attribute__((address_space(3))) void*)((char*)&Klds[bufi][0] + (size_t)u * 16), 16, 0, 0);
      const int vrow = u >> 3, vlin = u & 7;
      const int vslot = vlin ^ (vrow & 7);
      const f16* vsrc = Vh + (size_t)vrow * SEQ + kt + vslot * 8;
      __builtin_amdgcn_global_load_lds((const __attribute__((address_space(1))) void*)vsrc,
          (__attribute__((address_space(3))) void*)((char*)&Vlds[bufi][0] + (size_t)u * 16), 16, 0, 0);
    }
  };

  stage(0, 0);
  __syncthreads();

  for (int kt = 0; kt < SEQ; kt += 64) {
    const int buf = (kt >> 6) & 1;
    if (kt + 64 < SEQ) stage(buf ^ 1, kt + 64);

    const char* Kt = (const char*)Klds[buf];
    const char* Vt = (const char*)Vlds[buf];

    f32x4 s[4];
    __builtin_amdgcn_s_setprio(1);
#pragma unroll
    for (int nf = 0; nf < 4; nf++) {
      f32x4 a = f32x4{0.f, 0.f, 0.f, 0.f};
#pragma unroll
      for (int kd = 0; kd < 4; kd++) {
        const int row = nf * 16 + ll;
        f16x8 kf = *reinterpret_cast<const f16x8*>(
            Kt + row * 256 + ((((kd << 2) + lg) ^ (row & 7)) << 4));
        a = __builtin_amdgcn_mfma_f32_16x16x32_f16(kf, qf[kd], a, 0, 0, 0);
      }
      s[nf] = a;
    }
    __builtin_amdgcn_s_setprio(0);

    float mx = s[0][0];
#pragma unroll
    for (int nf = 0; nf < 4; nf++)
#pragma unroll
      for (int r = 0; r < 4; r++) mx = fmaxf(mx, s[nf][r]);

    if (!__all((int)(mx <= m_ + THR))) {
      float mr = fmaxf(mx, __shfl_xor(mx, 16, 64));
      mr = fmaxf(mr, __shfl_xor(mr, 32, 64));
      const float mn = fmaxf(m_, mr);
      const float corrq = __builtin_amdgcn_exp2f(m_ - mn);
      m_ = mn;
      l_ *= corrq;
#pragma unroll
      for (int r = 0; r < 4; r++) {
        const float c = __shfl(corrq, (lane & 48) | (lg * 4 + r), 64);
#pragma unroll
        for (int df = 0; df < 8; df++) o[df][r] *= c;
      }
    }

    float rs = 0.f;
#pragma unroll
    for (int nf = 0; nf < 4; nf++)
#pragma unroll
      for (int r = 0; r < 4; r++) {
        const float p = __builtin_amdgcn_exp2f(s[nf][r] - m_);
        s[nf][r] = p;
        rs += p;
      }
    rs += __shfl_xor(rs, 16, 64);
    rs += __shfl_xor(rs, 32, 64);
    l_ += rs;

    char* Pw = (char*)&Plds[w][0];
#pragma unroll
    for (int nf = 0; nf < 4; nf++) {
      union { f16 h[4]; ushort4 u4; } pk;
#pragma unroll
      for (int r = 0; r < 4; r++) pk.h[r] = (f16)s[nf][r];
      *reinterpret_cast<ushort4*>(Pw + ll * 128 + ((nf * 32 + lg * 8) ^ ((ll & 7) << 4))) = pk.u4;
    }

    f16x8 pf[2];
#pragma unroll
    for (int kf = 0; kf < 2; kf++)
      pf[kf] = *reinterpret_cast<const f16x8*>(Pw + ll * 128 + (((kf << 6) + (lg << 4)) ^ ((ll & 7) << 4)));

    __builtin_amdgcn_s_setprio(1);
#pragma unroll
    for (int kf = 0; kf < 2; kf++)
#pragma unroll
      for (int df = 0; df < 8; df++) {
        const int row = df * 16 + ll;
        f16x8 vf = *reinterpret_cast<const f16x8*>(
            Vt + row * 128 + ((((kf << 2) + lg) ^ (row & 7)) << 4));
        o[df] = __builtin_amdgcn_mfma_f32_16x16x32_f16(pf[kf], vf, o[df], 0, 0, 0);
      }
    __builtin_amdgcn_s_setprio(0);

    __syncthreads();
  }

  float inv[4];
#pragma unroll
  for (int r = 0; r < 4; r++) {
    const float lq = __shfl(l_, (lane & 48) | (lg * 4 + r), 64);
    inv[r] = 1.0f / lq;
  }
  f16* cb = ctx + ((size_t)(b * SEQ + q0) * NH + h) * HD;
#pragma unroll
  for (int df = 0; df < 8; df++)
#pragma unroll
    for (int r = 0; r < 4; r++)
      cb[(size_t)(lg * 4 + r) * (NH * HD) + df * 16 + ll] = (f16)(o[df][r] * inv[r]);
}

extern "C" void kernel_launch(void* const* d_in, const int* in_sizes, int n_in,
                              void* d_out, int out_size, void* d_ws, size_t ws_size,
                              hipStream_t stream) {
  (void)in_sizes; (void)n_in; (void)out_size;
  const float* x  = (const float*)d_in[0];
  const float* wq = (const float*)d_in[1];
  const float* wk = (const float*)d_in[2];
  const float* wv = (const float*)d_in[3];
  const float* wo = (const float*)d_in[4];
  float* out = (float*)d_out;

  const size_t SZ_X   = (size_t)MTOK * DMODEL * sizeof(f16);     // 33,554,432
  const size_t SZ_KV  = (size_t)MTOK * NKV * HD * sizeof(f16);   //  8,388,608
  const size_t SZ_WKV = (size_t)2048 * DMODEL * sizeof(f16);     // 16,777,216
  const size_t BASE   = 3 * SZ_X + 2 * SZ_KV;                    // 117.4 MB
  if (ws_size < BASE) return;

  char* ws = (char*)d_ws;
  f16* xh   = (f16*)ws;
  f16* wT   = (f16*)(ws + SZ_X);
  f16* Qb   = (f16*)(ws + 2 * SZ_X);
  f16* Kb   = (f16*)(ws + 3 * SZ_X);
  f16* VTb  = (f16*)(ws + 3 * SZ_X + SZ_KV);
  f16* wkvT = (f16*)(ws + BASE);            // +16.8 MB (paths A/B)
  f16* woT  = (f16*)(ws + BASE + SZ_WKV);   // +33.5 MB (path A)

  const float KSC2 = 0.08838834764831845f * 1.4426950408889634f;  // 1/sqrt(128)*log2(e)

  const bool pathA = ws_size >= BASE + SZ_WKV + SZ_X;
  const bool pathB = !pathA && ws_size >= BASE + SZ_WKV;

  if (pathA || pathB) {
    // one fused prep dispatch: x | wq^T | wk|wv^T (| wo^T in path A)
    const int grid = pathA ? 49152 : 32768;
    prep_k<<<dim3(grid), 256, 0, stream>>>(x, xh, wq, wT, wk, wv, wkvT, wo, woT, KSC2);
    gemm256_k<0><<<dim3((MTOK / 256) * (DMODEL / 256)), 512, 0, stream>>>(xh, wT, Qb, MTOK, DMODEL, DMODEL);
    gemm_kv8_k<<<dim3((MTOK / 128) * (2048 / 256)), 512, 0, stream>>>(xh, wkvT, Kb, VTb, MTOK, 2048, DMODEL);
    attn_k11<<<dim3(BATCH * NKV * (SEQ / 32)), 512, 0, stream>>>(Qb, Kb, VTb, xh);
    if (pathA) {
      gemm256_k<2><<<dim3((MTOK / 256) * (DMODEL / 256)), 512, 0, stream>>>(xh, woT, out, MTOK, DMODEL, DMODEL);
    } else {
      transpose_cvt_k<<<dim3(DMODEL / 32, DMODEL / 32), 256, 0, stream>>>(wo, wT, DMODEL, DMODEL, 1.0f);
      gemm256_k<2><<<dim3((MTOK / 256) * (DMODEL / 256)), 512, 0, stream>>>(xh, wT, out, MTOK, DMODEL, DMODEL);
    }
  } else {
    // fallback = round-10 sequence (wkv^T overwrites wT after gemm-Q)
    cvt_f32_f16_k<<<dim3(MTOK * DMODEL / 8 / 256), 256, 0, stream>>>(x, xh, MTOK * DMODEL / 8);
    transpose_cvt_k<<<dim3(DMODEL / 32, DMODEL / 32), 256, 0, stream>>>(wq, wT, DMODEL, DMODEL, KSC2);
    gemm256_k<0><<<dim3((MTOK / 256) * (DMODEL / 256)), 512, 0, stream>>>(xh, wT, Qb, MTOK, DMODEL, DMODEL);
    transpose_cvt2_k<<<dim3(NKV * HD / 32, DMODEL / 32, 2), 256, 0, stream>>>(wk, wv, wT, DMODEL, NKV * HD);
    gemm_kv8_k<<<dim3((MTOK / 128) * (2048 / 256)), 512, 0, stream>>>(xh, wT, Kb, VTb, MTOK, 2048, DMODEL);
    attn_k11<<<dim3(BATCH * NKV * (SEQ / 32)), 512, 0, stream>>>(Qb, Kb, VTb, xh);
    transpose_cvt_k<<<dim3(DMODEL / 32, DMODEL / 32), 256, 0, stream>>>(wo, wT, DMODEL, DMODEL, 1.0f);
    gemm256_k<2><<<dim3((MTOK / 256) * (DMODEL / 256)), 512, 0, stream>>>(xh, wT, out, MTOK, DMODEL, DMODEL);
  }
}

// Round 12
// 518.255 us; speedup vs baseline: 1.0685x; 1.0075x over previous
//
#include <hip/hip_runtime.h>
#include <math.h>

typedef _Float16 f16;
using f16x8 = __attribute__((ext_vector_type(8))) _Float16;
using f32x4 = __attribute__((ext_vector_type(4))) float;

#define BATCH 2
#define SEQ   2048
#define DMODEL 4096
#define NH    32
#define NKV   8
#define HD    128
#define MTOK  (BATCH*SEQ)

// ------------- fused prep: block-role by bid range -------------
__global__ __launch_bounds__(256) void prep_k(const float* __restrict__ x, f16* __restrict__ xh,
                                              const float* __restrict__ wq, f16* __restrict__ wqT,
                                              const float* __restrict__ wk, const float* __restrict__ wv,
                                              f16* __restrict__ wkvT,
                                              const float* __restrict__ wo, f16* __restrict__ woT,
                                              float scale) {
  __shared__ float tile[32][33];
  const int bid = blockIdx.x, t = threadIdx.x;
  if (bid < 8192) {
    const int i = bid * 256 + t;
    const float4* p = reinterpret_cast<const float4*>(x) + (size_t)i * 2;
    float4 a = p[0], b = p[1];
    f16x8 o = { (f16)a.x, (f16)a.y, (f16)a.z, (f16)a.w,
                (f16)b.x, (f16)b.y, (f16)b.z, (f16)b.w };
    reinterpret_cast<f16x8*>(xh)[i] = o;
    return;
  }
  const float* w; f16* dst; int Nd; float sc;
  int bb;
  if (bid < 24576)      { bb = bid - 8192;  w = wq; dst = wqT;  Nd = DMODEL; sc = scale; }
  else if (bid < 32768) { bb = bid - 24576; const int z = bb >> 12; bb &= 4095;
                          w = z ? wv : wk; dst = wkvT + (size_t)z * 1024 * DMODEL; Nd = 1024; sc = 1.0f; }
  else                  { bb = bid - 32768; w = wo; dst = woT; Nd = DMODEL; sc = 1.0f; }
  const int ntile = Nd >> 5;
  const int n0 = (bb % ntile) * 32, k0 = (bb / ntile) * 32;
  const int r = t >> 3, c4 = (t & 7) << 2;
  const float4 v = *reinterpret_cast<const float4*>(w + (size_t)(k0 + r) * Nd + n0 + c4);
  tile[r][c4 + 0] = v.x; tile[r][c4 + 1] = v.y; tile[r][c4 + 2] = v.z; tile[r][c4 + 3] = v.w;
  __syncthreads();
  union { f16 h[4]; ushort4 u4; } pk;
  pk.h[0] = (f16)(tile[c4 + 0][r] * sc);
  pk.h[1] = (f16)(tile[c4 + 1][r] * sc);
  pk.h[2] = (f16)(tile[c4 + 2][r] * sc);
  pk.h[3] = (f16)(tile[c4 + 3][r] * sc);
  *reinterpret_cast<ushort4*>(dst + (size_t)(n0 + r) * DMODEL + k0 + c4) = pk.u4;
}

// ------------- standalone transpose / convert (fallback paths) -------------
__global__ __launch_bounds__(256) void transpose_cvt_k(const float* __restrict__ w,
                                                       f16* __restrict__ wt, int Kd, int Nd,
                                                       float scale) {
  __shared__ float tile[32][33];
  const int t = threadIdx.x;
  const int n0 = blockIdx.x * 32, k0 = blockIdx.y * 32;
  const int r = t >> 3, c4 = (t & 7) << 2;
  const float4 v = *reinterpret_cast<const float4*>(w + (size_t)(k0 + r) * Nd + n0 + c4);
  tile[r][c4 + 0] = v.x; tile[r][c4 + 1] = v.y; tile[r][c4 + 2] = v.z; tile[r][c4 + 3] = v.w;
  __syncthreads();
  union { f16 h[4]; ushort4 u4; } pk;
  pk.h[0] = (f16)(tile[c4 + 0][r] * scale);
  pk.h[1] = (f16)(tile[c4 + 1][r] * scale);
  pk.h[2] = (f16)(tile[c4 + 2][r] * scale);
  pk.h[3] = (f16)(tile[c4 + 3][r] * scale);
  *reinterpret_cast<ushort4*>(wt + (size_t)(n0 + r) * Kd + k0 + c4) = pk.u4;
}

__global__ __launch_bounds__(256) void transpose_cvt2_k(const float* __restrict__ w0,
                                                        const float* __restrict__ w1,
                                                        f16* __restrict__ wt, int Kd, int Nd) {
  __shared__ float tile[32][33];
  const float* w = blockIdx.z ? w1 : w0;
  f16* dst = wt + (size_t)blockIdx.z * Nd * Kd;
  const int t = threadIdx.x;
  const int n0 = blockIdx.x * 32, k0 = blockIdx.y * 32;
  const int r = t >> 3, c4 = (t & 7) << 2;
  const float4 v = *reinterpret_cast<const float4*>(w + (size_t)(k0 + r) * Nd + n0 + c4);
  tile[r][c4 + 0] = v.x; tile[r][c4 + 1] = v.y; tile[r][c4 + 2] = v.z; tile[r][c4 + 3] = v.w;
  __syncthreads();
  union { f16 h[4]; ushort4 u4; } pk;
  pk.h[0] = (f16)tile[c4 + 0][r];
  pk.h[1] = (f16)tile[c4 + 1][r];
  pk.h[2] = (f16)tile[c4 + 2][r];
  pk.h[3] = (f16)tile[c4 + 3][r];
  *reinterpret_cast<ushort4*>(dst + (size_t)(n0 + r) * Kd + k0 + c4) = pk.u4;
}

__global__ __launch_bounds__(256) void cvt_f32_f16_k(const float* __restrict__ in,
                                                     f16* __restrict__ out, int n8) {
  int i = blockIdx.x * 256 + threadIdx.x;
  if (i >= n8) return;
  const float4* p = reinterpret_cast<const float4*>(in) + (size_t)i * 2;
  float4 a = p[0], b = p[1];
  f16x8 o = { (f16)a.x, (f16)a.y, (f16)a.z, (f16)a.w,
              (f16)b.x, (f16)b.y, (f16)b.z, (f16)b.w };
  reinterpret_cast<f16x8*>(out)[i] = o;
}

// ===== merged Q-proj (role 0: bid<256, 256^2 8-phase) + KV-proj (role 1: bid>=256, 128x256 8-phase) =====
__global__ __launch_bounds__(512, 2) void gemm_qkv_k(const f16* __restrict__ A,
                                                     const f16* __restrict__ wqT, f16* __restrict__ Qb,
                                                     const f16* __restrict__ wkvT,
                                                     f16* __restrict__ Kc, f16* __restrict__ Vt) {
  __shared__ __align__(16) char ldsb_raw[131072];   // union: roleQ 128 KB, roleKV 96 KB
  char* ldsb = ldsb_raw;

  const int bid0 = blockIdx.x;
  const int t = threadIdx.x, lane = t & 63, w = t >> 6;
  const int wm = w >> 2, wn = w & 3;
  const int ll = lane & 15, lg = lane >> 4;
  const int M = MTOK, K = DMODEL;
  const int NT = K >> 6;

  if (bid0 < 256) {
    // ---------------- role Q: gemm256 MODE 0 (N = DMODEL) ----------------
    const f16* BT = wqT;
    const int N = DMODEL;
    const int nbn = N >> 8;
    const int cpx = 256 >> 3, bid = bid0;
    const int swz = (bid & 7) * cpx + (bid >> 3);
    const int bm = swz / nbn, bn = swz % nbn;
    const size_t m0 = (size_t)bm << 8, n0 = (size_t)bn << 8;

    auto stage = [&](int bufI, int unit, int ktS) {
      const f16* base = (unit < 2) ? (A + (m0 + (size_t)(unit & 1) * 128) * (size_t)K)
                                   : (BT + (n0 + (size_t)(unit & 1) * 128) * (size_t)K);
#pragma unroll
      for (int rr = 0; rr < 2; rr++) {
        const int u = t + rr * 512;
        const int row = u >> 3, lin = u & 7;
        const int slot = lin ^ (row & 7);
        const f16* src = base + (size_t)row * K + ktS + slot * 8;
        char* dst = ldsb + (size_t)(bufI * 4 + unit) * 16384 + (size_t)(w * 64 + rr * 512) * 16;
        __builtin_amdgcn_global_load_lds((const __attribute__((address_space(1))) void*)src,
            (__attribute__((address_space(3))) void*)dst, 16, 0, 0);
      }
    };

    f32x4 acc[8][4];
#pragma unroll
    for (int i = 0; i < 8; i++)
#pragma unroll
      for (int j = 0; j < 4; j++) acc[i][j] = f32x4{0.f, 0.f, 0.f, 0.f};

    f16x8 af[4][2];
    f16x8 bfr[2][2][2];

    stage(0, 0, 0); stage(0, 2, 0); stage(0, 3, 0); stage(0, 1, 0);
    stage(1, 0, 64); stage(1, 2, 64); stage(1, 3, 64);
    asm volatile("s_waitcnt vmcnt(6)" ::: "memory");
    __builtin_amdgcn_sched_barrier(0);
    __builtin_amdgcn_s_barrier();

#define PH(RBUF, RDA, RDB, SBUF, SUNIT, STILE, VM, MH, NHQ) do {                          \
    if ((RDA) >= 0) {                                                                     \
      const char* ab = ldsb + (size_t)((RBUF) * 4 + (RDA)) * 16384;                       \
      _Pragma("unroll") for (int mi = 0; mi < 4; mi++)                                    \
        _Pragma("unroll") for (int kk = 0; kk < 2; kk++)                                  \
          af[mi][kk] = *reinterpret_cast<const f16x8*>(ab + (mi * 32 + wm * 16 + ll) * 128\
                               + ((((kk << 2) + lg) ^ (ll & 7)) << 4));                   \
    }                                                                                     \
    if ((RDB) >= 0) {                                                                     \
      const char* bb = ldsb + (size_t)((RBUF) * 4 + 2 + (RDB)) * 16384;                   \
      _Pragma("unroll") for (int ni = 0; ni < 2; ni++)                                    \
        _Pragma("unroll") for (int kk = 0; kk < 2; kk++)                                  \
          bfr[RDB][ni][kk] = *reinterpret_cast<const f16x8*>(bb +                         \
                               (wn * 32 + ni * 16 + ll) * 128                             \
                               + ((((kk << 2) + lg) ^ (ll & 7)) << 4));                   \
    }                                                                                     \
    stage((SBUF), (SUNIT), ((STILE) & (NT - 1)) << 6);                                    \
    if ((RDA) >= 0 && (RDB) >= 0)                                                         \
      asm volatile("s_waitcnt lgkmcnt(8)" ::: "memory");                                  \
    if (VM) { asm volatile("s_waitcnt vmcnt(6)" ::: "memory");                            \
              __builtin_amdgcn_sched_barrier(0); }                                        \
    __builtin_amdgcn_s_barrier();                                                         \
    asm volatile("s_waitcnt lgkmcnt(0)" ::: "memory");                                    \
    __builtin_amdgcn_sched_barrier(0);                                                    \
    __builtin_amdgcn_s_setprio(1);                                                        \
    _Pragma("unroll") for (int kk = 0; kk < 2; kk++)                                      \
      _Pragma("unroll") for (int mi = 0; mi < 4; mi++)                                    \
        _Pragma("unroll") for (int ni = 0; ni < 2; ni++)                                  \
          acc[(MH) * 4 + mi][(NHQ) * 2 + ni] = __builtin_amdgcn_mfma_f32_16x16x32_f16(    \
              af[mi][kk], bfr[NHQ][ni][kk], acc[(MH) * 4 + mi][(NHQ) * 2 + ni], 0, 0, 0); \
    __builtin_amdgcn_s_setprio(0);                                                        \
    __builtin_amdgcn_s_barrier();                                                         \
  } while (0)

    for (int tt = 0; tt < NT; tt += 2) {
      PH(0,  0,  0, 1, 1, tt + 1, false, 0, 0);
      PH(0, -1,  1, 0, 0, tt + 2, false, 0, 1);
      PH(0,  1, -1, 0, 2, tt + 2, false, 1, 0);
      PH(0, -1, -1, 0, 3, tt + 2, true , 1, 1);
      PH(1,  0,  0, 0, 1, tt + 2, false, 0, 0);
      PH(1, -1,  1, 1, 0, tt + 3, false, 0, 1);
      PH(1,  1, -1, 1, 2, tt + 3, false, 1, 0);
      PH(1, -1, -1, 1, 3, tt + 3, true , 1, 1);
    }
#undef PH

#pragma unroll
    for (int mh = 0; mh < 2; mh++)
#pragma unroll
      for (int mi = 0; mi < 4; mi++) {
        const size_t r0 = m0 + mh * 128 + mi * 32 + wm * 16 + lg * 4;
#pragma unroll
        for (int nh = 0; nh < 2; nh++)
#pragma unroll
          for (int ni = 0; ni < 2; ni++) {
            const size_t c = n0 + nh * 128 + wn * 32 + ni * 16 + ll;
            const f32x4 v = acc[mh * 4 + mi][nh * 2 + ni];
#pragma unroll
            for (int rr = 0; rr < 4; rr++) Qb[(r0 + rr) * N + c] = (f16)v[rr];
          }
      }
  } else {
    // ---------------- role KV: gemm_kv8 (N = 2048, BM=128 x BN=256) ----------------
    const f16* BT = wkvT;
    const int N = 2048;
    const int nbn = N >> 8;
    const int cpx = 256 >> 3, bid = bid0 - 256;
    const int swz = (bid & 7) * cpx + (bid >> 3);
    const int bm = swz / nbn, bn = swz % nbn;
    const size_t m0 = (size_t)bm << 7, n0 = (size_t)bn << 8;

    const int uoff[4] = {0, 8192, 16384, 32768};

    auto stage = [&](int bufI, int unit, int ktS) {
      char* dstb = ldsb + (size_t)bufI * 49152 + uoff[unit];
      if (unit < 2) {
        const f16* base = A + (m0 + (size_t)(unit & 1) * 64) * (size_t)K;
        const int row = t >> 3, lin = t & 7;
        const int slot = lin ^ (row & 7);
        const f16* src = base + (size_t)row * K + ktS + slot * 8;
        __builtin_amdgcn_global_load_lds((const __attribute__((address_space(1))) void*)src,
            (__attribute__((address_space(3))) void*)(dstb + (size_t)t * 16), 16, 0, 0);
      } else {
        const f16* base = BT + (n0 + (size_t)(unit & 1) * 128) * (size_t)K;
#pragma unroll
        for (int rr = 0; rr < 2; rr++) {
          const int u = t + rr * 512;
          const int row = u >> 3, lin = u & 7;
          const int slot = lin ^ (row & 7);
          const f16* src = base + (size_t)row * K + ktS + slot * 8;
          __builtin_amdgcn_global_load_lds((const __attribute__((address_space(1))) void*)src,
              (__attribute__((address_space(3))) void*)(dstb + (size_t)u * 16), 16, 0, 0);
        }
      }
    };

    f32x4 acc[4][4];
#pragma unroll
    for (int i = 0; i < 4; i++)
#pragma unroll
      for (int j = 0; j < 4; j++) acc[i][j] = f32x4{0.f, 0.f, 0.f, 0.f};

    f16x8 af[2][2];
    f16x8 bfr[2][2][2];

    stage(0, 0, 0); stage(0, 1, 0); stage(0, 2, 0); stage(0, 3, 0);
    stage(1, 0, 64); stage(1, 2, 64); stage(1, 3, 64);
    asm volatile("s_waitcnt vmcnt(5)" ::: "memory");
    __builtin_amdgcn_sched_barrier(0);
    __builtin_amdgcn_s_barrier();

#define PHK(RBUF, RDA, RDB, SBUF, SUNIT, STILE, VM, MH, NHQ) do {                         \
    if ((RDA) >= 0) {                                                                     \
      const char* ab = ldsb + (size_t)(RBUF) * 49152 + uoff[MH];                          \
      _Pragma("unroll") for (int mi2 = 0; mi2 < 2; mi2++)                                 \
        _Pragma("unroll") for (int kk = 0; kk < 2; kk++) {                                \
          const int ri = wm * 32 + mi2 * 16 + ll;                                         \
          af[mi2][kk] = *reinterpret_cast<const f16x8*>(ab + ri * 128                     \
                               + ((((kk << 2) + lg) ^ (ri & 7)) << 4));                   \
        }                                                                                 \
    }                                                                                     \
    if ((RDB) >= 0) {                                                                     \
      const char* bb = ldsb + (size_t)(RBUF) * 49152 + uoff[2 + (RDB)];                   \
      _Pragma("unroll") for (int ni2 = 0; ni2 < 2; ni2++)                                 \
        _Pragma("unroll") for (int kk = 0; kk < 2; kk++) {                                \
          const int ri = wn * 32 + ni2 * 16 + ll;                                         \
          bfr[RDB][ni2][kk] = *reinterpret_cast<const f16x8*>(bb + ri * 128               \
                               + ((((kk << 2) + lg) ^ (ri & 7)) << 4));                   \
        }                                                                                 \
    }                                                                                     \
    stage((SBUF), (SUNIT), ((STILE) & (NT - 1)) << 6);                                    \
    if (VM) { asm volatile("s_waitcnt vmcnt(5)" ::: "memory");                            \
              __builtin_amdgcn_sched_barrier(0); }                                        \
    __builtin_amdgcn_s_barrier();                                                        \
    asm volatile("s_waitcnt lgkmcnt(0)" ::: "memory");                                    \
    __builtin_amdgcn_sched_barrier(0);                                                    \
    __builtin_amdgcn_s_setprio(1);                                                        \
    _Pragma("unroll") for (int kk = 0; kk < 2; kk++)                                      \
      _Pragma("unroll") for (int mi2 = 0; mi2 < 2; mi2++)                                 \
        _Pragma("unroll") for (int ni2 = 0; ni2 < 2; ni2++)                               \
          acc[(MH) * 2 + mi2][(NHQ) * 2 + ni2] = __builtin_amdgcn_mfma_f32_16x16x32_f16(  \
              af[mi2][kk], bfr[NHQ][ni2][kk], acc[(MH) * 2 + mi2][(NHQ) * 2 + ni2],       \
              0, 0, 0);                                                                   \
    __builtin_amdgcn_s_setprio(0);                                                        \
    __builtin_amdgcn_s_barrier();                                                        \
  } while (0)

    for (int tt = 0; tt < NT; tt += 2) {
      PHK(0,  0,  0, 1, 1, tt + 1, false, 0, 0);
      PHK(0, -1,  1, 0, 0, tt + 2, false, 0, 1);
      PHK(0,  1, -1, 0, 2, tt + 2, false, 1, 0);
      PHK(0, -1, -1, 0, 3, tt + 2, true , 1, 1);
      PHK(1,  0,  0, 0, 1, tt + 2, false, 0, 0);
      PHK(1, -1,  1, 1, 0, tt + 3, false, 0, 1);
      PHK(1,  1, -1, 1, 2, tt + 3, false, 1, 0);
      PHK(1, -1, -1, 1, 3, tt + 3, true , 1, 1);
    }
#undef PHK

#pragma unroll
    for (int mh = 0; mh < 2; mh++)
#pragma unroll
      for (int mi2 = 0; mi2 < 2; mi2++) {
        const size_t r0 = m0 + mh * 64 + wm * 32 + mi2 * 16 + lg * 4;
#pragma unroll
        for (int nh = 0; nh < 2; nh++)
#pragma unroll
          for (int ni2 = 0; ni2 < 2; ni2++) {
            const size_t c = n0 + nh * 128 + wn * 32 + ni2 * 16 + ll;
            const f32x4 v = acc[mh * 2 + mi2][nh * 2 + ni2];
            if ((int)c < 1024) {
#pragma unroll
              for (int rr = 0; rr < 4; rr++) Kc[(r0 + rr) * 1024 + c] = (f16)v[rr];
            } else {
              const int nc = (int)c - 1024;
              const int kvh = nc >> 7, d = nc & 127;
              const int b = (int)(r0 >> 11), sc = (int)(r0 & 2047);
              union { f16 h[4]; ushort4 u4; } pk;
#pragma unroll
              for (int rr = 0; rr < 4; rr++) pk.h[rr] = (f16)v[rr];
              *reinterpret_cast<ushort4*>(Vt + (((size_t)(b * NKV + kvh) * HD + d) * SEQ + sc)) = pk.u4;
            }
          }
      }
  }
}

// ------------- standalone 8-phase KV GEMM (fallback paths) -------------
__global__ __launch_bounds__(512, 2) void gemm_kv8_k(const f16* __restrict__ A,
                                                     const f16* __restrict__ BT,
                                                     f16* __restrict__ Kc,
                                                     f16* __restrict__ Vt,
                                                     int M, int N, int K) {
  __shared__ f16 lds[2 * 24576];
  char* ldsb = (char*)lds;

  const int t = threadIdx.x, lane = t & 63, w = t >> 6;
  const int wm = w >> 2, wn = w & 3;
  const int ll = lane & 15, lg = lane >> 4;
  const int nbn = N >> 8;
  const int nwg = gridDim.x, cpx = nwg >> 3, bid = blockIdx.x;
  const int swz = (bid & 7) * cpx + (bid >> 3);
  const int bm = swz / nbn, bn = swz % nbn;
  const size_t m0 = (size_t)bm << 7, n0 = (size_t)bn << 8;
  const int NT = K >> 6;

  const int uoff[4] = {0, 8192, 16384, 32768};

  auto stage = [&](int bufI, int unit, int ktS) {
    char* dstb = ldsb + (size_t)bufI * 49152 + uoff[unit];
    if (unit < 2) {
      const f16* base = A + (m0 + (size_t)(unit & 1) * 64) * (size_t)K;
      const int row = t >> 3, lin = t & 7;
      const int slot = lin ^ (row & 7);
      const f16* src = base + (size_t)row * K + ktS + slot * 8;
      __builtin_amdgcn_global_load_lds((const __attribute__((address_space(1))) void*)src,
          (__attribute__((address_space(3))) void*)(dstb + (size_t)t * 16), 16, 0, 0);
    } else {
      const f16* base = BT + (n0 + (size_t)(unit & 1) * 128) * (size_t)K;
#pragma unroll
      for (int rr = 0; rr < 2; rr++) {
        const int u = t + rr * 512;
        const int row = u >> 3, lin = u & 7;
        const int slot = lin ^ (row & 7);
        const f16* src = base + (size_t)row * K + ktS + slot * 8;
        __builtin_amdgcn_global_load_lds((const __attribute__((address_space(1))) void*)src,
            (__attribute__((address_space(3))) void*)(dstb + (size_t)u * 16), 16, 0, 0);
      }
    }
  };

  f32x4 acc[4][4];
#pragma unroll
  for (int i = 0; i < 4; i++)
#pragma unroll
    for (int j = 0; j < 4; j++) acc[i][j] = f32x4{0.f, 0.f, 0.f, 0.f};

  f16x8 af[2][2];
  f16x8 bfr[2][2][2];

  stage(0, 0, 0); stage(0, 1, 0); stage(0, 2, 0); stage(0, 3, 0);
  stage(1, 0, 64); stage(1, 2, 64); stage(1, 3, 64);
  asm volatile("s_waitcnt vmcnt(5)" ::: "memory");
  __builtin_amdgcn_sched_barrier(0);
  __builtin_amdgcn_s_barrier();

#define PHK(RBUF, RDA, RDB, SBUF, SUNIT, STILE, VM, MH, NHQ) do {                         \
    if ((RDA) >= 0) {                                                                     \
      const char* ab = ldsb + (size_t)(RBUF) * 49152 + uoff[MH];                          \
      _Pragma("unroll") for (int mi2 = 0; mi2 < 2; mi2++)                                 \
        _Pragma("unroll") for (int kk = 0; kk < 2; kk++) {                                \
          const int ri = wm * 32 + mi2 * 16 + ll;                                         \
          af[mi2][kk] = *reinterpret_cast<const f16x8*>(ab + ri * 128                     \
                               + ((((kk << 2) + lg) ^ (ri & 7)) << 4));                   \
        }                                                                                 \
    }                                                                                     \
    if ((RDB) >= 0) {                                                                     \
      const char* bb = ldsb + (size_t)(RBUF) * 49152 + uoff[2 + (RDB)];                   \
      _Pragma("unroll") for (int ni2 = 0; ni2 < 2; ni2++)                                 \
        _Pragma("unroll") for (int kk = 0; kk < 2; kk++) {                                \
          const int ri = wn * 32 + ni2 * 16 + ll;                                         \
          bfr[RDB][ni2][kk] = *reinterpret_cast<const f16x8*>(bb + ri * 128               \
                               + ((((kk << 2) + lg) ^ (ri & 7)) << 4));                   \
        }                                                                                 \
    }                                                                                     \
    stage((SBUF), (SUNIT), ((STILE) & (NT - 1)) << 6);                                    \
    if (VM) { asm volatile("s_waitcnt vmcnt(5)" ::: "memory");                            \
              __builtin_amdgcn_sched_barrier(0); }                                        \
    __builtin_amdgcn_s_barrier();                                                         \
    asm volatile("s_waitcnt lgkmcnt(0)" ::: "memory");                                    \
    __builtin_amdgcn_sched_barrier(0);                                                    \
    __builtin_amdgcn_s_setprio(1);                                                        \
    _Pragma("unroll") for (int kk = 0; kk < 2; kk++)                                      \
      _Pragma("unroll") for (int mi2 = 0; mi2 < 2; mi2++)                                 \
        _Pragma("unroll") for (int ni2 = 0; ni2 < 2; ni2++)                               \
          acc[(MH) * 2 + mi2][(NHQ) * 2 + ni2] = __builtin_amdgcn_mfma_f32_16x16x32_f16(  \
              af[mi2][kk], bfr[NHQ][ni2][kk], acc[(MH) * 2 + mi2][(NHQ) * 2 + ni2],       \
              0, 0, 0);                                                                   \
    __builtin_amdgcn_s_setprio(0);                                                        \
    __builtin_amdgcn_s_barrier();                                                        \
  } while (0)

  for (int tt = 0; tt < NT; tt += 2) {
    PHK(0,  0,  0, 1, 1, tt + 1, false, 0, 0);
    PHK(0, -1,  1, 0, 0, tt + 2, false, 0, 1);
    PHK(0,  1, -1, 0, 2, tt + 2, false, 1, 0);
    PHK(0, -1, -1, 0, 3, tt + 2, true , 1, 1);
    PHK(1,  0,  0, 0, 1, tt + 2, false, 0, 0);
    PHK(1, -1,  1, 1, 0, tt + 3, false, 0, 1);
    PHK(1,  1, -1, 1, 2, tt + 3, false, 1, 0);
    PHK(1, -1, -1, 1, 3, tt + 3, true , 1, 1);
  }
#undef PHK

#pragma unroll
  for (int mh = 0; mh < 2; mh++)
#pragma unroll
    for (int mi2 = 0; mi2 < 2; mi2++) {
      const size_t r0 = m0 + mh * 64 + wm * 32 + mi2 * 16 + lg * 4;
#pragma unroll
      for (int nh = 0; nh < 2; nh++)
#pragma unroll
        for (int ni2 = 0; ni2 < 2; ni2++) {
          const size_t c = n0 + nh * 128 + wn * 32 + ni2 * 16 + ll;
          const f32x4 v = acc[mh * 2 + mi2][nh * 2 + ni2];
          if ((int)c < 1024) {
#pragma unroll
            for (int rr = 0; rr < 4; rr++) Kc[(r0 + rr) * 1024 + c] = (f16)v[rr];
          } else {
            const int nc = (int)c - 1024;
            const int kvh = nc >> 7, d = nc & 127;
            const int b = (int)(r0 >> 11), sc = (int)(r0 & 2047);
            union { f16 h[4]; ushort4 u4; } pk;
#pragma unroll
            for (int rr = 0; rr < 4; rr++) pk.h[rr] = (f16)v[rr];
            *reinterpret_cast<ushort4*>(Vt + (((size_t)(b * NKV + kvh) * HD + d) * SEQ + sc)) = pk.u4;
          }
        }
    }
}

// ------------- 256^2 8-phase GEMM (out projection + fallback Q) -------------
template<int MODE>
__global__ __launch_bounds__(512, 2) void gemm256_k(const f16* __restrict__ A,
                                                    const f16* __restrict__ BT,
                                                    void* __restrict__ Cv,
                                                    int M, int N, int K) {
  __shared__ f16 lds[2 * 4 * 128 * 64];
  char* ldsb = (char*)lds;

  const int t = threadIdx.x, lane = t & 63, w = t >> 6;
  const int wm = w >> 2, wn = w & 3;
  const int ll = lane & 15, lg = lane >> 4;
  const int nbn = N >> 8;
  const int nwg = gridDim.x, cpx = nwg >> 3, bid = blockIdx.x;
  const int swz = (bid & 7) * cpx + (bid >> 3);
  const int bm = swz / nbn, bn = swz % nbn;
  const size_t m0 = (size_t)bm << 8, n0 = (size_t)bn << 8;
  const int NT = K >> 6;

  auto stage = [&](int bufI, int unit, int ktS) {
    const f16* base = (unit < 2) ? (A + (m0 + (size_t)(unit & 1) * 128) * (size_t)K)
                                 : (BT + (n0 + (size_t)(unit & 1) * 128) * (size_t)K);
#pragma unroll
    for (int rr = 0; rr < 2; rr++) {
      const int u = t + rr * 512;
      const int row = u >> 3, lin = u & 7;
      const int slot = lin ^ (row & 7);
      const f16* src = base + (size_t)row * K + ktS + slot * 8;
      char* dst = ldsb + (size_t)(bufI * 4 + unit) * 16384 + (size_t)(w * 64 + rr * 512) * 16;
      __builtin_amdgcn_global_load_lds((const __attribute__((address_space(1))) void*)src,
          (__attribute__((address_space(3))) void*)dst, 16, 0, 0);
    }
  };

  f32x4 acc[8][4];
#pragma unroll
  for (int i = 0; i < 8; i++)
#pragma unroll
    for (int j = 0; j < 4; j++) acc[i][j] = f32x4{0.f, 0.f, 0.f, 0.f};

  f16x8 af[4][2];
  f16x8 bfr[2][2][2];

  stage(0, 0, 0); stage(0, 2, 0); stage(0, 3, 0); stage(0, 1, 0);
  stage(1, 0, 64); stage(1, 2, 64); stage(1, 3, 64);
  asm volatile("s_waitcnt vmcnt(6)" ::: "memory");
  __builtin_amdgcn_sched_barrier(0);
  __builtin_amdgcn_s_barrier();

#define PH(RBUF, RDA, RDB, SBUF, SUNIT, STILE, VM, MH, NHQ) do {                          \
    if ((RDA) >= 0) {                                                                     \
      const char* ab = ldsb + (size_t)((RBUF) * 4 + (RDA)) * 16384;                       \
      _Pragma("unroll") for (int mi = 0; mi < 4; mi++)                                    \
        _Pragma("unroll") for (int kk = 0; kk < 2; kk++)                                  \
          af[mi][kk] = *reinterpret_cast<const f16x8*>(ab + (mi * 32 + wm * 16 + ll) * 128\
                               + ((((kk << 2) + lg) ^ (ll & 7)) << 4));                   \
    }                                                                                     \
    if ((RDB) >= 0) {                                                                     \
      const char* bb = ldsb + (size_t)((RBUF) * 4 + 2 + (RDB)) * 16384;                   \
      _Pragma("unroll") for (int ni = 0; ni < 2; ni++)                                    \
        _Pragma("unroll") for (int kk = 0; kk < 2; kk++)                                  \
          bfr[RDB][ni][kk] = *reinterpret_cast<const f16x8*>(bb +                         \
                               (wn * 32 + ni * 16 + ll) * 128                             \
                               + ((((kk << 2) + lg) ^ (ll & 7)) << 4));                   \
    }                                                                                     \
    stage((SBUF), (SUNIT), ((STILE) & (NT - 1)) << 6);                                    \
    if ((RDA) >= 0 && (RDB) >= 0)                                                         \
      asm volatile("s_waitcnt lgkmcnt(8)" ::: "memory");                                  \
    if (VM) { asm volatile("s_waitcnt vmcnt(6)" ::: "memory");                            \
              __builtin_amdgcn_sched_barrier(0); }                                        \
    __builtin_amdgcn_s_barrier();                                                         \
    asm volatile("s_waitcnt lgkmcnt(0)" ::: "memory");                                    \
    __builtin_amdgcn_sched_barrier(0);                                                    \
    __builtin_amdgcn_s_setprio(1);                                                        \
    _Pragma("unroll") for (int kk = 0; kk < 2; kk++)                                      \
      _Pragma("unroll") for (int mi = 0; mi < 4; mi++)                                    \
        _Pragma("unroll") for (int ni = 0; ni < 2; ni++)                                  \
          acc[(MH) * 4 + mi][(NHQ) * 2 + ni] = __builtin_amdgcn_mfma_f32_16x16x32_f16(    \
              af[mi][kk], bfr[NHQ][ni][kk], acc[(MH) * 4 + mi][(NHQ) * 2 + ni], 0, 0, 0); \
    __builtin_amdgcn_s_setprio(0);                                                        \
    __builtin_amdgcn_s_barrier();                                                        \
  } while (0)

  for (int tt = 0; tt < NT; tt += 2) {
    PH(0,  0,  0, 1, 1, tt + 1, false, 0, 0);
    PH(0, -1,  1, 0, 0, tt + 2, false, 0, 1);
    PH(0,  1, -1, 0, 2, tt + 2, false, 1, 0);
    PH(0, -1, -1, 0, 3, tt + 2, true , 1, 1);
    PH(1,  0,  0, 0, 1, tt + 2, false, 0, 0);
    PH(1, -1,  1, 1, 0, tt + 3, false, 0, 1);
    PH(1,  1, -1, 1, 2, tt + 3, false, 1, 0);
    PH(1, -1, -1, 1, 3, tt + 3, true , 1, 1);
  }
#undef PH

#pragma unroll
  for (int mh = 0; mh < 2; mh++)
#pragma unroll
    for (int mi = 0; mi < 4; mi++) {
      const size_t r0 = m0 + mh * 128 + mi * 32 + wm * 16 + lg * 4;
#pragma unroll
      for (int nh = 0; nh < 2; nh++)
#pragma unroll
        for (int ni = 0; ni < 2; ni++) {
          const size_t c = n0 + nh * 128 + wn * 32 + ni * 16 + ll;
          const f32x4 v = acc[mh * 4 + mi][nh * 2 + ni];
          if (MODE == 0) {
            f16* C = (f16*)Cv;
#pragma unroll
            for (int rr = 0; rr < 4; rr++) C[(r0 + rr) * N + c] = (f16)v[rr];
          } else {
            float* C = (float*)Cv;
#pragma unroll
            for (int rr = 0; rr < 4; rr++) C[(r0 + rr) * N + c] = v[rr];
          }
        }
    }
}

// ------------- flash attention (proven: v7 + T5 setprio, 178 us) -------------
__global__ __launch_bounds__(512) void attn_k12(const f16* __restrict__ Q,
                                                const f16* __restrict__ Kb,
                                                const f16* __restrict__ VT,
                                                f16* __restrict__ ctx) {
  __shared__ f16 Klds[2][64 * 128];
  __shared__ f16 Vlds[2][128 * 64];
  __shared__ f16 Plds[8][16 * 64];

  const int t = threadIdx.x, lane = t & 63, w = t >> 6;
  const int bid = blockIdx.x;
  const int swz = (bid & 7) * 128 + (bid >> 3);
  const int qt = swz & 63, kvh = (swz >> 6) & 7, b = swz >> 9;
  const int h = kvh * 4 + (w & 3);
  const int q0 = qt * 32 + (w >> 2) * 16;
  const int ll = lane & 15, lg = lane >> 4;

  const f16* Qb = Q + ((size_t)(b * SEQ + q0) * NH + h) * HD;
  const f16* Kh = Kb + ((size_t)b * SEQ * NKV + kvh) * HD;
  const f16* Vh = VT + ((size_t)(b * NKV + kvh)) * HD * SEQ;

  f16x8 qf[4];
#pragma unroll
  for (int kd = 0; kd < 4; kd++)
    qf[kd] = *reinterpret_cast<const f16x8*>(Qb + (size_t)ll * (NH * HD) + kd * 32 + lg * 8);

  float m_ = -INFINITY;
  float l_ = 0.f;
  f32x4 o[8];
#pragma unroll
  for (int df = 0; df < 8; df++) o[df] = f32x4{0.f, 0.f, 0.f, 0.f};

  const float THR = 11.5416f;

  auto stage = [&](int bufi, int kt) {
#pragma unroll
    for (int rr = 0; rr < 2; rr++) {
      const int u = w * 128 + rr * 64 + lane;
      const int krow = u >> 4, klin = u & 15;
      const int kslot = klin ^ (krow & 7);
      const f16* ksrc = Kh + (size_t)(kt + krow) * (NKV * HD) + kslot * 8;
      __builtin_amdgcn_global_load_lds((const __attribute__((address_space(1))) void*)ksrc,
          (__attribute__((address_space(3))) void*)((char*)&Klds[bufi][0] + (size_t)u * 16), 16, 0, 0);
      const int vrow = u >> 3, vlin = u & 7;
      const int vslot = vlin ^ (vrow & 7);
      const f16* vsrc = Vh + (size_t)vrow * SEQ + kt + vslot * 8;
      __builtin_amdgcn_global_load_lds((const __attribute__((address_space(1))) void*)vsrc,
          (__attribute__((address_space(3))) void*)((char*)&Vlds[bufi][0] + (size_t)u * 16), 16, 0, 0);
    }
  };

  stage(0, 0);
  __syncthreads();

  for (int kt = 0; kt < SEQ; kt += 64) {
    const int buf = (kt >> 6) & 1;
    if (kt + 64 < SEQ) stage(buf ^ 1, kt + 64);

    const char* Kt = (const char*)Klds[buf];
    const char* Vt = (const char*)Vlds[buf];

    f32x4 s[4];
    __builtin_amdgcn_s_setprio(1);
#pragma unroll
    for (int nf = 0; nf < 4; nf++) {
      f32x4 a = f32x4{0.f, 0.f, 0.f, 0.f};
#pragma unroll
      for (int kd = 0; kd < 4; kd++) {
        const int row = nf * 16 + ll;
        f16x8 kf = *reinterpret_cast<const f16x8*>(
            Kt + row * 256 + ((((kd << 2) + lg) ^ (row & 7)) << 4));
        a = __builtin_amdgcn_mfma_f32_16x16x32_f16(kf, qf[kd], a, 0, 0, 0);
      }
      s[nf] = a;
    }
    __builtin_amdgcn_s_setprio(0);

    float mx = s[0][0];
#pragma unroll
    for (int nf = 0; nf < 4; nf++)
#pragma unroll
      for (int r = 0; r < 4; r++) mx = fmaxf(mx, s[nf][r]);

    if (!__all((int)(mx <= m_ + THR))) {
      float mr = fmaxf(mx, __shfl_xor(mx, 16, 64));
      mr = fmaxf(mr, __shfl_xor(mr, 32, 64));
      const float mn = fmaxf(m_, mr);
      const float corrq = __builtin_amdgcn_exp2f(m_ - mn);
      m_ = mn;
      l_ *= corrq;
#pragma unroll
      for (int r = 0; r < 4; r++) {
        const float c = __shfl(corrq, (lane & 48) | (lg * 4 + r), 64);
#pragma unroll
        for (int df = 0; df < 8; df++) o[df][r] *= c;
      }
    }

    float rs = 0.f;
#pragma unroll
    for (int nf = 0; nf < 4; nf++)
#pragma unroll
      for (int r = 0; r < 4; r++) {
        const float p = __builtin_amdgcn_exp2f(s[nf][r] - m_);
        s[nf][r] = p;
        rs += p;
      }
    rs += __shfl_xor(rs, 16, 64);
    rs += __shfl_xor(rs, 32, 64);
    l_ += rs;

    char* Pw = (char*)&Plds[w][0];
#pragma unroll
    for (int nf = 0; nf < 4; nf++) {
      union { f16 h[4]; ushort4 u4; } pk;
#pragma unroll
      for (int r = 0; r < 4; r++) pk.h[r] = (f16)s[nf][r];
      *reinterpret_cast<ushort4*>(Pw + ll * 128 + ((nf * 32 + lg * 8) ^ ((ll & 7) << 4))) = pk.u4;
    }

    f16x8 pf[2];
#pragma unroll
    for (int kf = 0; kf < 2; kf++)
      pf[kf] = *reinterpret_cast<const f16x8*>(Pw + ll * 128 + (((kf << 6) + (lg << 4)) ^ ((ll & 7) << 4)));

    __builtin_amdgcn_s_setprio(1);
#pragma unroll
    for (int kf = 0; kf < 2; kf++)
#pragma unroll
      for (int df = 0; df < 8; df++) {
        const int row = df * 16 + ll;
        f16x8 vf = *reinterpret_cast<const f16x8*>(
            Vt + row * 128 + ((((kf << 2) + lg) ^ (row & 7)) << 4));
        o[df] = __builtin_amdgcn_mfma_f32_16x16x32_f16(pf[kf], vf, o[df], 0, 0, 0);
      }
    __builtin_amdgcn_s_setprio(0);

    __syncthreads();
  }

  float inv[4];
#pragma unroll
  for (int r = 0; r < 4; r++) {
    const float lq = __shfl(l_, (lane & 48) | (lg * 4 + r), 64);
    inv[r] = 1.0f / lq;
  }
  f16* cb = ctx + ((size_t)(b * SEQ + q0) * NH + h) * HD;
#pragma unroll
  for (int df = 0; df < 8; df++)
#pragma unroll
    for (int r = 0; r < 4; r++)
      cb[(size_t)(lg * 4 + r) * (NH * HD) + df * 16 + ll] = (f16)(o[df][r] * inv[r]);
}

extern "C" void kernel_launch(void* const* d_in, const int* in_sizes, int n_in,
                              void* d_out, int out_size, void* d_ws, size_t ws_size,
                              hipStream_t stream) {
  (void)in_sizes; (void)n_in; (void)out_size;
  const float* x  = (const float*)d_in[0];
  const float* wq = (const float*)d_in[1];
  const float* wk = (const float*)d_in[2];
  const float* wv = (const float*)d_in[3];
  const float* wo = (const float*)d_in[4];
  float* out = (float*)d_out;

  const size_t SZ_X   = (size_t)MTOK * DMODEL * sizeof(f16);
  const size_t SZ_KV  = (size_t)MTOK * NKV * HD * sizeof(f16);
  const size_t SZ_WKV = (size_t)2048 * DMODEL * sizeof(f16);
  const size_t BASE   = 3 * SZ_X + 2 * SZ_KV;
  if (ws_size < BASE) return;

  char* ws = (char*)d_ws;
  f16* xh   = (f16*)ws;
  f16* wT   = (f16*)(ws + SZ_X);
  f16* Qb   = (f16*)(ws + 2 * SZ_X);
  f16* Kb   = (f16*)(ws + 3 * SZ_X);
  f16* VTb  = (f16*)(ws + 3 * SZ_X + SZ_KV);
  f16* wkvT = (f16*)(ws + BASE);
  f16* woT  = (f16*)(ws + BASE + SZ_WKV);

  const float KSC2 = 0.08838834764831845f * 1.4426950408889634f;

  const bool pathA = ws_size >= BASE + SZ_WKV + SZ_X;
  const bool pathB = !pathA && ws_size >= BASE + SZ_WKV;

  if (pathA) {
    prep_k<<<dim3(49152), 256, 0, stream>>>(x, xh, wq, wT, wk, wv, wkvT, wo, woT, KSC2);
    // merged Q + KV projections: 512 blocks (role by bid)
    gemm_qkv_k<<<dim3(512), 512, 0, stream>>>(xh, wT, Qb, wkvT, Kb, VTb);
    attn_k12<<<dim3(BATCH * NKV * (SEQ / 32)), 512, 0, stream>>>(Qb, Kb, VTb, xh);
    gemm256_k<2><<<dim3((MTOK / 256) * (DMODEL / 256)), 512, 0, stream>>>(xh, woT, out, MTOK, DMODEL, DMODEL);
  } else if (pathB) {
    prep_k<<<dim3(32768), 256, 0, stream>>>(x, xh, wq, wT, wk, wv, wkvT, wo, woT, KSC2);
    gemm256_k<0><<<dim3((MTOK / 256) * (DMODEL / 256)), 512, 0, stream>>>(xh, wT, Qb, MTOK, DMODEL, DMODEL);
    gemm_kv8_k<<<dim3((MTOK / 128) * (2048 / 256)), 512, 0, stream>>>(xh, wkvT, Kb, VTb, MTOK, 2048, DMODEL);
    attn_k12<<<dim3(BATCH * NKV * (SEQ / 32)), 512, 0, stream>>>(Qb, Kb, VTb, xh);
    transpose_cvt_k<<<dim3(DMODEL / 32, DMODEL / 32), 256, 0, stream>>>(wo, wT, DMODEL, DMODEL, 1.0f);
    gemm256_k<2><<<dim3((MTOK / 256) * (DMODEL / 256)), 512, 0, stream>>>(xh, wT, out, MTOK, DMODEL, DMODEL);
  } else {
    cvt_f32_f16_k<<<dim3(MTOK * DMODEL / 8 / 256), 256, 0, stream>>>(x, xh, MTOK * DMODEL / 8);
    transpose_cvt_k<<<dim3(DMODEL / 32, DMODEL / 32), 256, 0, stream>>>(wq, wT, DMODEL, DMODEL, KSC2);
    gemm256_k<0><<<dim3((MTOK / 256) * (DMODEL / 256)), 512, 0, stream>>>(xh, wT, Qb, MTOK, DMODEL, DMODEL);
    transpose_cvt2_k<<<dim3(NKV * HD / 32, DMODEL / 32, 2), 256, 0, stream>>>(wk, wv, wT, DMODEL, NKV * HD);
    gemm_kv8_k<<<dim3((MTOK / 128) * (2048 / 256)), 512, 0, stream>>>(xh, wT, Kb, VTb, MTOK, 2048, DMODEL);
    attn_k12<<<dim3(BATCH * NKV * (SEQ / 32)), 512, 0, stream>>>(Qb, Kb, VTb, xh);
    transpose_cvt_k<<<dim3(DMODEL / 32, DMODEL / 32), 256, 0, stream>>>(wo, wT, DMODEL, DMODEL, 1.0f);
    gemm256_k<2><<<dim3((MTOK / 256) * (DMODEL / 256)), 512, 0, stream>>>(xh, wT, out, MTOK, DMODEL, DMODEL);
  }
}